// Round 4
// baseline (539.890 us; speedup 1.0000x reference)
//
#include <hip/hip_runtime.h>
#include <hip/hip_bf16.h>

#define E_EDGES 120000
#define NUM_NODES 12000

typedef __attribute__((ext_vector_type(8))) short bfrag;          // 8 bf16
typedef __attribute__((ext_vector_type(8))) unsigned short ushort8;
typedef __attribute__((ext_vector_type(4))) float f32x4;

#define INV_SQRT3 0.57735026918962576f
#define SQRT2_C   1.41421356237309515f
#define N_0E_C    0.14433756729740643f   /* 1/sqrt(48) */
#define NV_C      0.14433756729740643f   /* sqrt(3/48)*1/sqrt(3) = 1/sqrt(48) */
#define WSCALE    0.08838834764831845f   /* 1/sqrt(128) */

__device__ __forceinline__ unsigned short f2bf(float f) {
    union { float f; unsigned int u; } v; v.f = f;
    unsigned int r = v.u + 0x7fffu + ((v.u >> 16) & 1u);
    return (unsigned short)(r >> 16);
}

__device__ __forceinline__ ushort8 pack8(f32x4 a, f32x4 b) {
    ushort8 o;
    o[0] = f2bf(a.x); o[1] = f2bf(a.y); o[2] = f2bf(a.z); o[3] = f2bf(a.w);
    o[4] = f2bf(b.x); o[5] = f2bf(b.y); o[6] = f2bf(b.z); o[7] = f2bf(b.w);
    return o;
}

// ---- Kernel: w_emb (128 x 3072) -> Bt in fragment-consumption order.
__global__ void k_wt(const float* __restrict__ w_emb, unsigned short* __restrict__ Bt) {
    int o = blockIdx.x * 256 + threadIdx.x;
    if (o >= 3072 * 128) return;
    int t = o >> 11;
    int c = (o >> 3) & 255;
    int j = o & 7;
    int kb = c >> 6;
    int quad = (c >> 4) & 3;
    int col = c & 15;
    int k = kb * 32 + quad * 8 + j;
    int n = t * 16 + col;
    Bt[o] = f2bf(w_emb[k * 3072 + n] * WSCALE);
}

// ---- Kernel: per-edge prep (y0 PRE-multiplied -> merged accumulators)
// rT rows: 0..31 xs*y0 | 32..47 vdot*inv3 | 48..79 xs | 80..127 xv*y0
__global__ void k_prep(const float* __restrict__ x, const float* __restrict__ edge_attr,
                       const float* __restrict__ Yij, const int* __restrict__ edge_index,
                       unsigned short* __restrict__ emb, float* __restrict__ rT,
                       float* __restrict__ cnt) {
    int e = blockIdx.x * 256 + threadIdx.x;
    if (e >= E_EDGES) return;
    int dst = edge_index[e];
    int src = edge_index[E_EDGES + e];
    f32x4 y = *(const f32x4*)(Yij + 4 * (long)e);
    float y0 = y.x, y1a = y.y, y1b = y.z, y1c = y.w;
    const float* xd = x + (long)dst * 80;
    const float* xs = x + (long)src * 80;
    const float* ea = edge_attr + (long)e * 64;

    ushort8* embp = (ushort8*)(emb + (long)e * 128);

    float xsv[80];
#pragma unroll
    for (int i = 0; i < 80; i += 4) {
        f32x4 v = *(const f32x4*)(xs + i);
        xsv[i] = v.x; xsv[i + 1] = v.y; xsv[i + 2] = v.z; xsv[i + 3] = v.w;
    }
#pragma unroll
    for (int cb = 0; cb < 4; ++cb) {
        f32x4 a = *(const f32x4*)(xd + cb * 8);
        f32x4 b = *(const f32x4*)(xd + cb * 8 + 4);
        embp[cb] = pack8(a, b);
    }
#pragma unroll
    for (int cb = 0; cb < 4; ++cb) {
        f32x4 a, b;
        a.x = xsv[cb * 8 + 0]; a.y = xsv[cb * 8 + 1]; a.z = xsv[cb * 8 + 2]; a.w = xsv[cb * 8 + 3];
        b.x = xsv[cb * 8 + 4]; b.y = xsv[cb * 8 + 5]; b.z = xsv[cb * 8 + 6]; b.w = xsv[cb * 8 + 7];
        embp[4 + cb] = pack8(a, b);
    }
#pragma unroll
    for (int cb = 0; cb < 8; ++cb) {
        f32x4 a = *(const f32x4*)(ea + cb * 8);
        f32x4 b = *(const f32x4*)(ea + cb * 8 + 4);
        embp[8 + cb] = pack8(a, b);
    }
#pragma unroll
    for (int u = 0; u < 32; ++u) rT[(long)u * E_EDGES + e] = xsv[u] * y0;
#pragma unroll
    for (int u = 0; u < 16; ++u)
        rT[(long)(32 + u) * E_EDGES + e] =
            (xsv[32 + 3 * u] * y1a + xsv[33 + 3 * u] * y1b + xsv[34 + 3 * u] * y1c) * INV_SQRT3;
#pragma unroll
    for (int u = 0; u < 32; ++u) rT[(long)(48 + u) * E_EDGES + e] = xsv[u];
#pragma unroll
    for (int j = 0; j < 48; ++j) rT[(long)(80 + j) * E_EDGES + e] = xsv[32 + j] * y0;
    atomicAdd(cnt + dst, 1.0f);
}

// ---- Kernel: fused GEMM + u-contraction, R0 structure with the 48-chunk
// sweep SPLIT across 2 blocks at the group boundary:
//   half 0: chunks  0..23 (W1 16 + W2 8)   -> s0,s1 (W1 term), g (W2 term)
//   half 1: chunks 24..47 (W3 8 + W4 4 + W5 8 + W6 4) -> s0,s1 (W3), g (W4), t5, v
// Each u-contraction group is complete within its half; halves merge via the
// existing atomicAdd scatter. Grid 938 -> 1876 blocks: occupancy was GRID-
// limited (3.66 blocks/CU); now LDS-limited at 5 resident blocks/CU
// (20 waves/CU), ~2.7x the latency-hiding. Cost: +50% atomics, emb read 2x.
__global__ __launch_bounds__(256, 5) void k_gemm(
    const unsigned short* __restrict__ emb, const unsigned short* __restrict__ Bt,
    const float* __restrict__ rT, const int* __restrict__ edge_index,
    const float* __restrict__ Yij, float* __restrict__ summed) {
    const int lane = threadIdx.x & 63;
    const int wave = threadIdx.x >> 6;
    const int et = blockIdx.x >> 1;
    const int h  = blockIdx.x & 1;
    long e0 = (long)et * 128 + (long)wave * 32;
    const bool dup = (e0 + 32 > E_EDGES);
    if (dup) e0 = E_EDGES - 32;
    const int col = lane & 15, quad = lane >> 4;

    __shared__ __align__(16) char lds[2][16384];

    // A fragments, register-resident for the whole sweep
    bfrag A[2][4];
#pragma unroll
    for (int s = 0; s < 2; ++s) {
        const unsigned short* ap = emb + (e0 + s * 16 + col) * 128 + quad * 8;
#pragma unroll
        for (int kb = 0; kb < 4; ++kb) A[s][kb] = *(const bfrag*)(ap + kb * 32);
    }

    const size_t cbase = (size_t)h * 24 * 16384;
    auto stage = [&](int ci) {
        const char* g = (const char*)Bt + cbase + (size_t)ci * 16384 + wave * 4096 + lane * 16;
        char* l = &lds[ci & 1][wave * 4096];
#pragma unroll
        for (int j = 0; j < 4; ++j)
            __builtin_amdgcn_global_load_lds(
                (const __attribute__((address_space(1))) unsigned int*)(g + j * 1024),
                (__attribute__((address_space(3))) unsigned int*)(l + j * 1024), 16, 0, 0);
    };

    const float* rbase = rT + e0 + quad * 4;
    auto loadw = [&](int r, f32x4& a, f32x4& b) {
        const float* p = rbase + (long)r * E_EDGES;
        a = *(const f32x4*)(p);
        b = *(const f32x4*)(p + 16);
    };

    f32x4 z = {0.f, 0.f, 0.f, 0.f};
    auto tile = [&](const char* lt, f32x4& c0, f32x4& c1) {
        bfrag B0 = *(const bfrag*)(lt + lane * 16);
        bfrag B1 = *(const bfrag*)(lt + lane * 16 + 1024);
        bfrag B2 = *(const bfrag*)(lt + lane * 16 + 2048);
        bfrag B3 = *(const bfrag*)(lt + lane * 16 + 3072);
        c0 = z; c1 = z;
        c0 = __builtin_amdgcn_mfma_f32_16x16x32_bf16(A[0][0], B0, c0, 0, 0, 0);
        c1 = __builtin_amdgcn_mfma_f32_16x16x32_bf16(A[1][0], B0, c1, 0, 0, 0);
        c0 = __builtin_amdgcn_mfma_f32_16x16x32_bf16(A[0][1], B1, c0, 0, 0, 0);
        c1 = __builtin_amdgcn_mfma_f32_16x16x32_bf16(A[1][1], B1, c1, 0, 0, 0);
        c0 = __builtin_amdgcn_mfma_f32_16x16x32_bf16(A[0][2], B2, c0, 0, 0, 0);
        c1 = __builtin_amdgcn_mfma_f32_16x16x32_bf16(A[1][2], B2, c1, 0, 0, 0);
        c0 = __builtin_amdgcn_mfma_f32_16x16x32_bf16(A[0][3], B3, c0, 0, 0, 0);
        c1 = __builtin_amdgcn_mfma_f32_16x16x32_bf16(A[1][3], B3, c1, 0, 0, 0);
    };

    stage(0);
    int cidx = 0;
    auto nextbuf = [&]() -> const char* {
        __syncthreads();
        if (cidx + 1 < 24) stage(cidx + 1);
        const char* b = lds[cidx & 1];
        ++cidx;
        return b;
    };

    f32x4 c0, c1;

    if (h == 0) {
        f32x4 acc_s0[2] = {z, z}, acc_s1[2] = {z, z}, acc_g[2] = {z, z};
        // W1: chunks 0..15, rows 2j,2j+1 -> acc_s
        {
            f32x4 p0a, p0b, p1a, p1b;
            loadw(0, p0a, p0b); loadw(1, p1a, p1b);
#pragma unroll 1
            for (int j = 0; j < 16; ++j) {
                const char* buf = nextbuf();
                f32x4 w0a = p0a, w0b = p0b, w1a = p1a, w1b = p1b;
                int nr = (j < 15) ? (2 * j + 2) : 0;
                loadw(nr, p0a, p0b); loadw(nr + 1, p1a, p1b);
                tile(buf,         c0, c1); acc_s0[0] += c0 * w0a; acc_s0[1] += c1 * w0b;
                tile(buf + 4096,  c0, c1); acc_s1[0] += c0 * w0a; acc_s1[1] += c1 * w0b;
                tile(buf + 8192,  c0, c1); acc_s0[0] += c0 * w1a; acc_s0[1] += c1 * w1b;
                tile(buf + 12288, c0, c1); acc_s1[0] += c0 * w1a; acc_s1[1] += c1 * w1b;
            }
        }
        // W2: chunks 16..23, rows 4j..4j+3 -> acc_g
        {
            f32x4 pa[4], pb[4];
#pragma unroll
            for (int i = 0; i < 4; ++i) loadw(i, pa[i], pb[i]);
#pragma unroll 1
            for (int j = 0; j < 8; ++j) {
                const char* buf = nextbuf();
                f32x4 wa[4], wb[4];
#pragma unroll
                for (int i = 0; i < 4; ++i) { wa[i] = pa[i]; wb[i] = pb[i]; }
                int nr = (j < 7) ? (4 * j + 4) : 0;
#pragma unroll
                for (int i = 0; i < 4; ++i) loadw(nr + i, pa[i], pb[i]);
#pragma unroll
                for (int i = 0; i < 4; ++i) {
                    tile(buf + i * 4096, c0, c1);
                    acc_g[0] += c0 * wa[i]; acc_g[1] += c1 * wb[i];
                }
            }
        }
        if (dup) return;
#pragma unroll
        for (int s = 0; s < 2; ++s) {
            long eb = e0 + s * 16 + quad * 4;
#pragma unroll
            for (int r = 0; r < 4; ++r) {
                long e = eb + r;
                int d = edge_index[e];
                float* base = summed + (long)d * 96;
                atomicAdd(base + col,       N_0E_C * acc_s0[s][r]);
                atomicAdd(base + col + 16,  N_0E_C * acc_s1[s][r]);
                atomicAdd(base + 32 + col,  N_0E_C * acc_g[s][r]);
            }
        }
    } else {
        f32x4 acc_s0[2] = {z, z}, acc_s1[2] = {z, z}, acc_g[2] = {z, z}, acc_t5[2] = {z, z};
        f32x4 acc_v[2][3] = {{z, z, z}, {z, z, z}};
        // W3: chunks 0..7 (global 24..31), rows 32+2j,33+2j -> acc_s
        {
            f32x4 p0a, p0b, p1a, p1b;
            loadw(32, p0a, p0b); loadw(33, p1a, p1b);
#pragma unroll 1
            for (int j = 0; j < 8; ++j) {
                const char* buf = nextbuf();
                f32x4 w0a = p0a, w0b = p0b, w1a = p1a, w1b = p1b;
                int nr = (j < 7) ? (32 + 2 * j + 2) : 32;
                loadw(nr, p0a, p0b); loadw(nr + 1, p1a, p1b);
                tile(buf,         c0, c1); acc_s0[0] += c0 * w0a; acc_s0[1] += c1 * w0b;
                tile(buf + 4096,  c0, c1); acc_s1[0] += c0 * w0a; acc_s1[1] += c1 * w0b;
                tile(buf + 8192,  c0, c1); acc_s0[0] += c0 * w1a; acc_s0[1] += c1 * w1b;
                tile(buf + 12288, c0, c1); acc_s1[0] += c0 * w1a; acc_s1[1] += c1 * w1b;
            }
        }
        // W4: chunks 8..11 (global 32..35), rows 32+4j+i -> acc_g
        {
            f32x4 pa[4], pb[4];
#pragma unroll
            for (int i = 0; i < 4; ++i) loadw(32 + i, pa[i], pb[i]);
#pragma unroll 1
            for (int j = 0; j < 4; ++j) {
                const char* buf = nextbuf();
                f32x4 wa[4], wb[4];
#pragma unroll
                for (int i = 0; i < 4; ++i) { wa[i] = pa[i]; wb[i] = pb[i]; }
                int nr = (j < 3) ? (32 + 4 * j + 4) : 32;
#pragma unroll
                for (int i = 0; i < 4; ++i) loadw(nr + i, pa[i], pb[i]);
#pragma unroll
                for (int i = 0; i < 4; ++i) {
                    tile(buf + i * 4096, c0, c1);
                    acc_g[0] += c0 * wa[i]; acc_g[1] += c1 * wb[i];
                }
            }
        }
        // W5: chunks 12..19 (global 36..43), rows 48+4j+i -> acc_t5
        {
            f32x4 pa[4], pb[4];
#pragma unroll
            for (int i = 0; i < 4; ++i) loadw(48 + i, pa[i], pb[i]);
#pragma unroll 1
            for (int j = 0; j < 8; ++j) {
                const char* buf = nextbuf();
                f32x4 wa[4], wb[4];
#pragma unroll
                for (int i = 0; i < 4; ++i) { wa[i] = pa[i]; wb[i] = pb[i]; }
                int nr = (j < 7) ? (48 + 4 * j + 4) : 48;
#pragma unroll
                for (int i = 0; i < 4; ++i) loadw(nr + i, pa[i], pb[i]);
#pragma unroll
                for (int i = 0; i < 4; ++i) {
                    tile(buf + i * 4096, c0, c1);
                    acc_t5[0] += c0 * wa[i]; acc_t5[1] += c1 * wb[i];
                }
            }
        }
        // W6: chunks 20..23 (global 44..47), u=4j+i, rows 80+3u+k -> acc_v[k]
        {
            f32x4 va[3], vb[3];
#pragma unroll
            for (int k = 0; k < 3; ++k) loadw(80 + k, va[k], vb[k]);
#pragma unroll 1
            for (int j = 0; j < 4; ++j) {
                const char* buf = nextbuf();
#pragma unroll
                for (int i = 0; i < 4; ++i) {
                    f32x4 wa[3], wb[3];
#pragma unroll
                    for (int k = 0; k < 3; ++k) { wa[k] = va[k]; wb[k] = vb[k]; }
                    int un = 4 * j + i + 1; if (un > 15) un = 0;
#pragma unroll
                    for (int k = 0; k < 3; ++k) loadw(80 + 3 * un + k, va[k], vb[k]);
                    tile(buf + i * 4096, c0, c1);
#pragma unroll
                    for (int k = 0; k < 3; ++k) {
                        acc_v[0][k] += c0 * wa[k];
                        acc_v[1][k] += c1 * wb[k];
                    }
                }
            }
        }
        if (dup) return;
#pragma unroll
        for (int s = 0; s < 2; ++s) {
            long eb = e0 + s * 16 + quad * 4;
#pragma unroll
            for (int r = 0; r < 4; ++r) {
                long e = eb + r;
                int d = edge_index[e];
                float* base = summed + (long)d * 96;
                float y1a = Yij[4 * e + 1], y1b = Yij[4 * e + 2], y1c = Yij[4 * e + 3];
                atomicAdd(base + col,       N_0E_C * acc_s0[s][r]);
                atomicAdd(base + col + 16,  N_0E_C * acc_s1[s][r]);
                atomicAdd(base + 32 + col,  N_0E_C * acc_g[s][r]);
                float t5 = acc_t5[s][r];
                atomicAdd(base + 48 + col * 3 + 0, NV_C * (t5 * y1a + acc_v[s][0][r]));
                atomicAdd(base + 48 + col * 3 + 1, NV_C * (t5 * y1b + acc_v[s][1][r]));
                atomicAdd(base + 48 + col * 3 + 2, NV_C * (t5 * y1c + acc_v[s][2][r]));
            }
        }
    }
}

// ---- Kernel: mean, relu-gate, residual
__global__ void k_final(const float* __restrict__ x, const float* __restrict__ summed,
                        const float* __restrict__ cnt, float* __restrict__ out) {
    int tid = blockIdx.x * 256 + threadIdx.x;
    if (tid >= NUM_NODES * 80) return;
    int n = tid / 80, c = tid % 80;
    float m = fmaxf(cnt[n], 1.0f);
    float inv = 1.0f / m;
    float val;
    if (c < 32) {
        val = SQRT2_C * fmaxf(summed[(long)n * 96 + c] * inv, 0.0f);
    } else {
        int j = c - 32;
        int w = j / 3;
        float g = SQRT2_C * fmaxf(summed[(long)n * 96 + 32 + w] * inv, 0.0f);
        val = summed[(long)n * 96 + 48 + j] * inv * g;
    }
    out[tid] = x[tid] + val;
}

extern "C" void kernel_launch(void* const* d_in, const int* in_sizes, int n_in,
                              void* d_out, int out_size, void* d_ws, size_t ws_size,
                              hipStream_t stream) {
    const float* x         = (const float*)d_in[0];
    const float* edge_attr = (const float*)d_in[1];
    const float* Yij       = (const float*)d_in[2];
    const int*   edge_index= (const int*)d_in[3];
    const float* w_emb     = (const float*)d_in[4];
    float* out = (float*)d_out;

    char* ws = (char*)d_ws;
    size_t off = 0;
    unsigned short* emb = (unsigned short*)(ws + off); off += (size_t)E_EDGES * 128 * 2;
    unsigned short* Bt  = (unsigned short*)(ws + off); off += (size_t)3072 * 128 * 2;
    off = (off + 255) & ~(size_t)255;
    float* rT     = (float*)(ws + off); off += (size_t)128 * E_EDGES * 4;
    size_t zoff = off;
    float* summed = (float*)(ws + off); off += (size_t)NUM_NODES * 96 * 4;
    float* cnt    = (float*)(ws + off); off += (size_t)NUM_NODES * 4;

    hipMemsetAsync(ws + zoff, 0, (size_t)NUM_NODES * 97 * 4, stream);
    k_wt  <<<(3072 * 128 + 255) / 256, 256, 0, stream>>>(w_emb, Bt);
    k_prep<<<(E_EDGES + 255) / 256, 256, 0, stream>>>(x, edge_attr, Yij, edge_index, emb, rT, cnt);
    k_gemm<<<2 * ((E_EDGES + 127) / 128), 256, 0, stream>>>(emb, Bt, rT, edge_index, Yij, summed);
    k_final<<<(NUM_NODES * 80 + 255) / 256, 256, 0, stream>>>(x, summed, cnt, out);
}

// Round 5
// 450.281 us; speedup vs baseline: 1.1990x; 1.1990x over previous
//
#include <hip/hip_runtime.h>
#include <hip/hip_bf16.h>

#define E_EDGES 120000
#define NUM_NODES 12000

typedef __attribute__((ext_vector_type(8))) short bfrag;          // 8 bf16
typedef __attribute__((ext_vector_type(8))) unsigned short ushort8;
typedef __attribute__((ext_vector_type(4))) float f32x4;

#define INV_SQRT3 0.57735026918962576f
#define SQRT2_C   1.41421356237309515f
#define N_0E_C    0.14433756729740643f   /* 1/sqrt(48) */
#define NV_C      0.14433756729740643f   /* sqrt(3/48)*1/sqrt(3) = 1/sqrt(48) */
#define WSCALE    0.08838834764831845f   /* 1/sqrt(128) */

__device__ __forceinline__ unsigned short f2bf(float f) {
    union { float f; unsigned int u; } v; v.f = f;
    unsigned int r = v.u + 0x7fffu + ((v.u >> 16) & 1u);
    return (unsigned short)(r >> 16);
}

__device__ __forceinline__ ushort8 pack8(f32x4 a, f32x4 b) {
    ushort8 o;
    o[0] = f2bf(a.x); o[1] = f2bf(a.y); o[2] = f2bf(a.z); o[3] = f2bf(a.w);
    o[4] = f2bf(b.x); o[5] = f2bf(b.y); o[6] = f2bf(b.z); o[7] = f2bf(b.w);
    return o;
}

// ---- Kernel: w_emb (128 x 3072) -> Bt in fragment-consumption order.
__global__ void k_wt(const float* __restrict__ w_emb, unsigned short* __restrict__ Bt) {
    int o = blockIdx.x * 256 + threadIdx.x;
    if (o >= 3072 * 128) return;
    int t = o >> 11;
    int c = (o >> 3) & 255;
    int j = o & 7;
    int kb = c >> 6;
    int quad = (c >> 4) & 3;
    int col = c & 15;
    int k = kb * 32 + quad * 8 + j;
    int n = t * 16 + col;
    Bt[o] = f2bf(w_emb[k * 3072 + n] * WSCALE);
}

// ---- Counting sort by dst: count -> scan -> scatter ----
__global__ void k_count(const int* __restrict__ edge_index, float* __restrict__ cnt) {
    int e = blockIdx.x * 256 + threadIdx.x;
    if (e >= E_EDGES) return;
    atomicAdd(cnt + edge_index[e], 1.0f);
}

__global__ void k_scan(const float* __restrict__ cnt, int* __restrict__ offs) {
    __shared__ int psum[256];
    int t = threadIdx.x;
    const int SEG = (NUM_NODES + 255) / 256;  // 47
    int lo = t * SEG;
    int hi = lo + SEG; if (hi > NUM_NODES) hi = NUM_NODES;
    int s = 0;
    for (int i = lo; i < hi; ++i) s += (int)cnt[i];
    psum[t] = s;
    __syncthreads();
    if (t == 0) {
        int acc = 0;
        for (int i = 0; i < 256; ++i) { int v = psum[i]; psum[i] = acc; acc += v; }
    }
    __syncthreads();
    int acc = psum[t];
    for (int i = lo; i < hi; ++i) { offs[i] = acc; acc += (int)cnt[i]; }
}

__global__ void k_scatter(const int* __restrict__ edge_index, const int* __restrict__ offs,
                          int* __restrict__ cursor, int* __restrict__ perm_src,
                          int* __restrict__ dsts) {
    int e = blockIdx.x * 256 + threadIdx.x;
    if (e >= E_EDGES) return;
    int d = edge_index[e];
    int p = offs[d] + atomicAdd(cursor + d, 1);
    perm_src[p] = e;
    dsts[p] = d;
}

// ---- Kernel: per-edge prep in SORTED position space (y0 pre-multiplied).
// Thread handles sorted position p; gathers original edge inputs (full-line
// gathers), writes all outputs contiguously at p -> same coalescing as R0.
// rT rows: 0..31 xs*y0 | 32..47 vdot*inv3 | 48..79 xs | 80..127 xv*y0
__global__ void k_prep(const float* __restrict__ x, const float* __restrict__ edge_attr,
                       const float* __restrict__ Yij, const int* __restrict__ edge_index,
                       const int* __restrict__ perm_src, const int* __restrict__ dsts,
                       unsigned short* __restrict__ emb, float* __restrict__ rT,
                       f32x4* __restrict__ ys) {
    int p = blockIdx.x * 256 + threadIdx.x;
    if (p >= E_EDGES) return;
    int eid = perm_src[p];
    int dst = dsts[p];
    int src = edge_index[E_EDGES + eid];
    f32x4 y = *(const f32x4*)(Yij + 4 * (long)eid);
    float y0 = y.x, y1a = y.y, y1b = y.z, y1c = y.w;
    const float* xd = x + (long)dst * 80;
    const float* xs = x + (long)src * 80;
    const float* ea = edge_attr + (long)eid * 64;

    ushort8* embp = (ushort8*)(emb + (long)p * 128);

    float xsv[80];
#pragma unroll
    for (int i = 0; i < 80; i += 4) {
        f32x4 v = *(const f32x4*)(xs + i);
        xsv[i] = v.x; xsv[i + 1] = v.y; xsv[i + 2] = v.z; xsv[i + 3] = v.w;
    }
#pragma unroll
    for (int cb = 0; cb < 4; ++cb) {
        f32x4 a = *(const f32x4*)(xd + cb * 8);
        f32x4 b = *(const f32x4*)(xd + cb * 8 + 4);
        embp[cb] = pack8(a, b);
    }
#pragma unroll
    for (int cb = 0; cb < 4; ++cb) {
        f32x4 a, b;
        a.x = xsv[cb * 8 + 0]; a.y = xsv[cb * 8 + 1]; a.z = xsv[cb * 8 + 2]; a.w = xsv[cb * 8 + 3];
        b.x = xsv[cb * 8 + 4]; b.y = xsv[cb * 8 + 5]; b.z = xsv[cb * 8 + 6]; b.w = xsv[cb * 8 + 7];
        embp[4 + cb] = pack8(a, b);
    }
#pragma unroll
    for (int cb = 0; cb < 8; ++cb) {
        f32x4 a = *(const f32x4*)(ea + cb * 8);
        f32x4 b = *(const f32x4*)(ea + cb * 8 + 4);
        embp[8 + cb] = pack8(a, b);
    }
#pragma unroll
    for (int u = 0; u < 32; ++u) rT[(long)u * E_EDGES + p] = xsv[u] * y0;
#pragma unroll
    for (int u = 0; u < 16; ++u)
        rT[(long)(32 + u) * E_EDGES + p] =
            (xsv[32 + 3 * u] * y1a + xsv[33 + 3 * u] * y1b + xsv[34 + 3 * u] * y1c) * INV_SQRT3;
#pragma unroll
    for (int u = 0; u < 32; ++u) rT[(long)(48 + u) * E_EDGES + p] = xsv[u];
#pragma unroll
    for (int j = 0; j < 48; ++j) rT[(long)(80 + j) * E_EDGES + p] = xsv[32 + j] * y0;
    ys[p] = y;
}

// ---- Kernel: fused GEMM + u-contraction — R0 structure VERBATIM.
// Edges arrive dst-sorted: each block's 128 edges span few contiguous nodes,
// so epilogue atomics hit hot L2 lines. Bijective chunked XCD swizzle keeps
// consecutive blocks (consecutive node ranges) on the same XCD -> summed
// lines stay in one XCD's L2 instead of ping-ponging across 8.
__global__ __launch_bounds__(256, 4) void k_gemm(
    const unsigned short* __restrict__ emb, const unsigned short* __restrict__ Bt,
    const float* __restrict__ rT, const int* __restrict__ dsts,
    const f32x4* __restrict__ ys, float* __restrict__ summed) {
    const int lane = threadIdx.x & 63;
    const int wave = threadIdx.x >> 6;
    // Bijective chunked XCD swizzle (m204 form): NB=938, q=117, r=2.
    const int NB = (E_EDGES + 127) / 128;
    const int q = NB >> 3, r = NB & 7;
    int hb = blockIdx.x;
    int xcd = hb & 7, ii = hb >> 3;
    int lb = (xcd < r ? xcd * (q + 1) : r * (q + 1) + (xcd - r) * q) + ii;
    long e0 = (long)lb * 128 + (long)wave * 32;
    const bool dup = (e0 + 32 > E_EDGES);
    if (dup) e0 = E_EDGES - 32;
    const int col = lane & 15, quad = lane >> 4;

    __shared__ __align__(16) char lds[2][16384];

    // A fragments, register-resident for the whole sweep
    bfrag A[2][4];
#pragma unroll
    for (int s = 0; s < 2; ++s) {
        const unsigned short* ap = emb + (e0 + s * 16 + col) * 128 + quad * 8;
#pragma unroll
        for (int kb = 0; kb < 4; ++kb) A[s][kb] = *(const bfrag*)(ap + kb * 32);
    }

    auto stage = [&](int ci) {
        const char* g = (const char*)Bt + (size_t)ci * 16384 + wave * 4096 + lane * 16;
        char* l = &lds[ci & 1][wave * 4096];
#pragma unroll
        for (int j = 0; j < 4; ++j)
            __builtin_amdgcn_global_load_lds(
                (const __attribute__((address_space(1))) unsigned int*)(g + j * 1024),
                (__attribute__((address_space(3))) unsigned int*)(l + j * 1024), 16, 0, 0);
    };

    f32x4 z = {0.f, 0.f, 0.f, 0.f};
    f32x4 acc_s0[2] = {z, z}, acc_s1[2] = {z, z}, acc_g[2] = {z, z}, acc_t5[2] = {z, z};
    f32x4 acc_v[2][3] = {{z, z, z}, {z, z, z}};

    const float* rbase = rT + e0 + quad * 4;
    auto loadw = [&](int r_, f32x4& a, f32x4& b) {
        const float* p = rbase + (long)r_ * E_EDGES;
        a = *(const f32x4*)(p);
        b = *(const f32x4*)(p + 16);
    };

    auto tile = [&](const char* lt, f32x4& c0, f32x4& c1) {
        bfrag B0 = *(const bfrag*)(lt + lane * 16);
        bfrag B1 = *(const bfrag*)(lt + lane * 16 + 1024);
        bfrag B2 = *(const bfrag*)(lt + lane * 16 + 2048);
        bfrag B3 = *(const bfrag*)(lt + lane * 16 + 3072);
        c0 = z; c1 = z;
        c0 = __builtin_amdgcn_mfma_f32_16x16x32_bf16(A[0][0], B0, c0, 0, 0, 0);
        c1 = __builtin_amdgcn_mfma_f32_16x16x32_bf16(A[1][0], B0, c1, 0, 0, 0);
        c0 = __builtin_amdgcn_mfma_f32_16x16x32_bf16(A[0][1], B1, c0, 0, 0, 0);
        c1 = __builtin_amdgcn_mfma_f32_16x16x32_bf16(A[1][1], B1, c1, 0, 0, 0);
        c0 = __builtin_amdgcn_mfma_f32_16x16x32_bf16(A[0][2], B2, c0, 0, 0, 0);
        c1 = __builtin_amdgcn_mfma_f32_16x16x32_bf16(A[1][2], B2, c1, 0, 0, 0);
        c0 = __builtin_amdgcn_mfma_f32_16x16x32_bf16(A[0][3], B3, c0, 0, 0, 0);
        c1 = __builtin_amdgcn_mfma_f32_16x16x32_bf16(A[1][3], B3, c1, 0, 0, 0);
    };

    stage(0);
    int cidx = 0;
    auto nextbuf = [&]() -> const char* {
        __syncthreads();
        if (cidx + 1 < 48) stage(cidx + 1);
        const char* b = lds[cidx & 1];
        ++cidx;
        return b;
    };

    f32x4 c0, c1;

    // W1: chunks 0..15, rows 2j,2j+1 -> acc_s
    {
        f32x4 p0a, p0b, p1a, p1b;
        loadw(0, p0a, p0b); loadw(1, p1a, p1b);
#pragma unroll 1
        for (int j = 0; j < 16; ++j) {
            const char* buf = nextbuf();
            f32x4 w0a = p0a, w0b = p0b, w1a = p1a, w1b = p1b;
            int nr = (j < 15) ? (2 * j + 2) : 0;
            loadw(nr, p0a, p0b); loadw(nr + 1, p1a, p1b);
            tile(buf,         c0, c1); acc_s0[0] += c0 * w0a; acc_s0[1] += c1 * w0b;
            tile(buf + 4096,  c0, c1); acc_s1[0] += c0 * w0a; acc_s1[1] += c1 * w0b;
            tile(buf + 8192,  c0, c1); acc_s0[0] += c0 * w1a; acc_s0[1] += c1 * w1b;
            tile(buf + 12288, c0, c1); acc_s1[0] += c0 * w1a; acc_s1[1] += c1 * w1b;
        }
    }
    // W2: chunks 16..23, rows 4j..4j+3 -> acc_g
    {
        f32x4 pa[4], pb[4];
#pragma unroll
        for (int i = 0; i < 4; ++i) loadw(i, pa[i], pb[i]);
#pragma unroll 1
        for (int j = 0; j < 8; ++j) {
            const char* buf = nextbuf();
            f32x4 wa[4], wb[4];
#pragma unroll
            for (int i = 0; i < 4; ++i) { wa[i] = pa[i]; wb[i] = pb[i]; }
            int nr = (j < 7) ? (4 * j + 4) : 0;
#pragma unroll
            for (int i = 0; i < 4; ++i) loadw(nr + i, pa[i], pb[i]);
#pragma unroll
            for (int i = 0; i < 4; ++i) {
                tile(buf + i * 4096, c0, c1);
                acc_g[0] += c0 * wa[i]; acc_g[1] += c1 * wb[i];
            }
        }
    }
    // W3: chunks 24..31, rows 32+2j,33+2j -> acc_s
    {
        f32x4 p0a, p0b, p1a, p1b;
        loadw(32, p0a, p0b); loadw(33, p1a, p1b);
#pragma unroll 1
        for (int j = 0; j < 8; ++j) {
            const char* buf = nextbuf();
            f32x4 w0a = p0a, w0b = p0b, w1a = p1a, w1b = p1b;
            int nr = (j < 7) ? (32 + 2 * j + 2) : 32;
            loadw(nr, p0a, p0b); loadw(nr + 1, p1a, p1b);
            tile(buf,         c0, c1); acc_s0[0] += c0 * w0a; acc_s0[1] += c1 * w0b;
            tile(buf + 4096,  c0, c1); acc_s1[0] += c0 * w0a; acc_s1[1] += c1 * w0b;
            tile(buf + 8192,  c0, c1); acc_s0[0] += c0 * w1a; acc_s0[1] += c1 * w1b;
            tile(buf + 12288, c0, c1); acc_s1[0] += c0 * w1a; acc_s1[1] += c1 * w1b;
        }
    }
    // W4: chunks 32..35, rows 32+4j+i -> acc_g
    {
        f32x4 pa[4], pb[4];
#pragma unroll
        for (int i = 0; i < 4; ++i) loadw(32 + i, pa[i], pb[i]);
#pragma unroll 1
        for (int j = 0; j < 4; ++j) {
            const char* buf = nextbuf();
            f32x4 wa[4], wb[4];
#pragma unroll
            for (int i = 0; i < 4; ++i) { wa[i] = pa[i]; wb[i] = pb[i]; }
            int nr = (j < 3) ? (32 + 4 * j + 4) : 32;
#pragma unroll
            for (int i = 0; i < 4; ++i) loadw(nr + i, pa[i], pb[i]);
#pragma unroll
            for (int i = 0; i < 4; ++i) {
                tile(buf + i * 4096, c0, c1);
                acc_g[0] += c0 * wa[i]; acc_g[1] += c1 * wb[i];
            }
        }
    }
    // W5: chunks 36..43, rows 48+4j+i -> acc_t5
    {
        f32x4 pa[4], pb[4];
#pragma unroll
        for (int i = 0; i < 4; ++i) loadw(48 + i, pa[i], pb[i]);
#pragma unroll 1
        for (int j = 0; j < 8; ++j) {
            const char* buf = nextbuf();
            f32x4 wa[4], wb[4];
#pragma unroll
            for (int i = 0; i < 4; ++i) { wa[i] = pa[i]; wb[i] = pb[i]; }
            int nr = (j < 7) ? (48 + 4 * j + 4) : 48;
#pragma unroll
            for (int i = 0; i < 4; ++i) loadw(nr + i, pa[i], pb[i]);
#pragma unroll
            for (int i = 0; i < 4; ++i) {
                tile(buf + i * 4096, c0, c1);
                acc_t5[0] += c0 * wa[i]; acc_t5[1] += c1 * wb[i];
            }
        }
    }
    // W6: chunks 44..47, u=4j+i, rows 80+3u+k -> acc_v[k]
    {
        f32x4 va[3], vb[3];
#pragma unroll
        for (int k = 0; k < 3; ++k) loadw(80 + k, va[k], vb[k]);
#pragma unroll 1
        for (int j = 0; j < 4; ++j) {
            const char* buf = nextbuf();
#pragma unroll
            for (int i = 0; i < 4; ++i) {
                f32x4 wa[3], wb[3];
#pragma unroll
                for (int k = 0; k < 3; ++k) { wa[k] = va[k]; wb[k] = vb[k]; }
                int un = 4 * j + i + 1; if (un > 15) un = 0;
#pragma unroll
                for (int k = 0; k < 3; ++k) loadw(80 + 3 * un + k, va[k], vb[k]);
                tile(buf + i * 4096, c0, c1);
#pragma unroll
                for (int k = 0; k < 3; ++k) {
                    acc_v[0][k] += c0 * wa[k];
                    acc_v[1][k] += c1 * wb[k];
                }
            }
        }
    }

    if (dup) return;
    // Epilogue: scale + atomic scatter into summed[node][96] (dst-sorted ->
    // consecutive e share d -> atomics hit hot lines in this XCD's L2)
#pragma unroll
    for (int s = 0; s < 2; ++s) {
        long eb = e0 + s * 16 + quad * 4;
#pragma unroll
        for (int r_ = 0; r_ < 4; ++r_) {
            long e = eb + r_;
            int d = dsts[e];
            float* base = summed + (long)d * 96;
            f32x4 y = ys[e];
            float y1a = y.y, y1b = y.z, y1c = y.w;
            atomicAdd(base + col,       N_0E_C * acc_s0[s][r_]);
            atomicAdd(base + col + 16,  N_0E_C * acc_s1[s][r_]);
            atomicAdd(base + 32 + col,  N_0E_C * acc_g[s][r_]);
            float t5 = acc_t5[s][r_];
            atomicAdd(base + 48 + col * 3 + 0, NV_C * (t5 * y1a + acc_v[s][0][r_]));
            atomicAdd(base + 48 + col * 3 + 1, NV_C * (t5 * y1b + acc_v[s][1][r_]));
            atomicAdd(base + 48 + col * 3 + 2, NV_C * (t5 * y1c + acc_v[s][2][r_]));
        }
    }
}

// ---- Kernel: mean, relu-gate, residual
__global__ void k_final(const float* __restrict__ x, const float* __restrict__ summed,
                        const float* __restrict__ cnt, float* __restrict__ out) {
    int tid = blockIdx.x * 256 + threadIdx.x;
    if (tid >= NUM_NODES * 80) return;
    int n = tid / 80, c = tid % 80;
    float m = fmaxf(cnt[n], 1.0f);
    float inv = 1.0f / m;
    float val;
    if (c < 32) {
        val = SQRT2_C * fmaxf(summed[(long)n * 96 + c] * inv, 0.0f);
    } else {
        int j = c - 32;
        int w = j / 3;
        float g = SQRT2_C * fmaxf(summed[(long)n * 96 + 32 + w] * inv, 0.0f);
        val = summed[(long)n * 96 + 48 + j] * inv * g;
    }
    out[tid] = x[tid] + val;
}

extern "C" void kernel_launch(void* const* d_in, const int* in_sizes, int n_in,
                              void* d_out, int out_size, void* d_ws, size_t ws_size,
                              hipStream_t stream) {
    const float* x         = (const float*)d_in[0];
    const float* edge_attr = (const float*)d_in[1];
    const float* Yij       = (const float*)d_in[2];
    const int*   edge_index= (const int*)d_in[3];
    const float* w_emb     = (const float*)d_in[4];
    float* out = (float*)d_out;

    char* ws = (char*)d_ws;
    size_t off = 0;
    unsigned short* emb = (unsigned short*)(ws + off); off += (size_t)E_EDGES * 128 * 2;
    unsigned short* Bt  = (unsigned short*)(ws + off); off += (size_t)3072 * 128 * 2;
    off = (off + 255) & ~(size_t)255;
    float* rT      = (float*)(ws + off); off += (size_t)128 * E_EDGES * 4;
    f32x4* ys      = (f32x4*)(ws + off); off += (size_t)E_EDGES * 16;
    int*   perm_src= (int*)(ws + off);   off += (size_t)E_EDGES * 4;
    int*   dsts    = (int*)(ws + off);   off += (size_t)E_EDGES * 4;
    int*   offs    = (int*)(ws + off);   off += (size_t)NUM_NODES * 4;
    size_t zoff = off;
    float* summed  = (float*)(ws + off); off += (size_t)NUM_NODES * 96 * 4;
    float* cnt     = (float*)(ws + off); off += (size_t)NUM_NODES * 4;
    int*   cursor  = (int*)(ws + off);   off += (size_t)NUM_NODES * 4;

    hipMemsetAsync(ws + zoff, 0, (size_t)NUM_NODES * 98 * 4, stream);
    k_wt     <<<(3072 * 128 + 255) / 256, 256, 0, stream>>>(w_emb, Bt);
    k_count  <<<(E_EDGES + 255) / 256, 256, 0, stream>>>(edge_index, cnt);
    k_scan   <<<1, 256, 0, stream>>>(cnt, offs);
    k_scatter<<<(E_EDGES + 255) / 256, 256, 0, stream>>>(edge_index, offs, cursor, perm_src, dsts);
    k_prep   <<<(E_EDGES + 255) / 256, 256, 0, stream>>>(x, edge_attr, Yij, edge_index,
                                                         perm_src, dsts, emb, rT, ys);
    k_gemm   <<<(E_EDGES + 127) / 128, 256, 0, stream>>>(emb, Bt, rT, dsts, ys, summed);
    k_final  <<<(NUM_NODES * 80 + 255) / 256, 256, 0, stream>>>(x, summed, cnt, out);
}

// Round 6
// 336.906 us; speedup vs baseline: 1.6025x; 1.3365x over previous
//
#include <hip/hip_runtime.h>
#include <hip/hip_bf16.h>

#define E_EDGES 120000
#define NUM_NODES 12000

typedef __attribute__((ext_vector_type(8))) short bfrag;          // 8 bf16
typedef __attribute__((ext_vector_type(8))) unsigned short ushort8;
typedef __attribute__((ext_vector_type(4))) float f32x4;

#define INV_SQRT3 0.57735026918962576f
#define SQRT2_C   1.41421356237309515f
#define N_0E_C    0.14433756729740643f   /* 1/sqrt(48) */
#define NV_C      0.14433756729740643f   /* sqrt(3/48)*1/sqrt(3) = 1/sqrt(48) */
#define WSCALE    0.08838834764831845f   /* 1/sqrt(128) */

__device__ __forceinline__ unsigned short f2bf(float f) {
    union { float f; unsigned int u; } v; v.f = f;
    unsigned int r = v.u + 0x7fffu + ((v.u >> 16) & 1u);
    return (unsigned short)(r >> 16);
}

__device__ __forceinline__ ushort8 pack8(f32x4 a, f32x4 b) {
    ushort8 o;
    o[0] = f2bf(a.x); o[1] = f2bf(a.y); o[2] = f2bf(a.z); o[3] = f2bf(a.w);
    o[4] = f2bf(b.x); o[5] = f2bf(b.y); o[6] = f2bf(b.z); o[7] = f2bf(b.w);
    return o;
}

// ---- Kernel: w_emb (128 x 3072) -> Bt in fragment-consumption order.
__global__ void k_wt(const float* __restrict__ w_emb, unsigned short* __restrict__ Bt) {
    int o = blockIdx.x * 256 + threadIdx.x;
    if (o >= 3072 * 128) return;
    int t = o >> 11;
    int c = (o >> 3) & 255;
    int j = o & 7;
    int kb = c >> 6;
    int quad = (c >> 4) & 3;
    int col = c & 15;
    int k = kb * 32 + quad * 8 + j;
    int n = t * 16 + col;
    Bt[o] = f2bf(w_emb[k * 3072 + n] * WSCALE);
}

// ---- Counting sort by dst (for the REDUCTION pass only; k_gemm stays in
// original edge order): count -> scan -> scatter
__global__ void k_count(const int* __restrict__ edge_index, int* __restrict__ cnt) {
    int e = blockIdx.x * 256 + threadIdx.x;
    if (e >= E_EDGES) return;
    atomicAdd(cnt + edge_index[e], 1);
}

__global__ void k_scan(const int* __restrict__ cnt, int* __restrict__ offs) {
    __shared__ int psum[256];
    int t = threadIdx.x;
    const int SEG = (NUM_NODES + 255) / 256;  // 47
    int lo = t * SEG;
    int hi = lo + SEG; if (hi > NUM_NODES) hi = NUM_NODES;
    int s = 0;
    for (int i = lo; i < hi; ++i) s += cnt[i];
    psum[t] = s;
    __syncthreads();
    if (t == 0) {
        int acc = 0;
        for (int i = 0; i < 256; ++i) { int v = psum[i]; psum[i] = acc; acc += v; }
    }
    __syncthreads();
    int acc = psum[t];
    for (int i = lo; i < hi; ++i) { offs[i] = acc; acc += cnt[i]; }
    if (t == 255) offs[NUM_NODES] = acc;   // == E_EDGES
}

__global__ void k_scatter(const int* __restrict__ edge_index, const int* __restrict__ offs,
                          int* __restrict__ cursor, int* __restrict__ perm_src) {
    int e = blockIdx.x * 256 + threadIdx.x;
    if (e >= E_EDGES) return;
    int d = edge_index[e];
    int p = offs[d] + atomicAdd(cursor + d, 1);
    perm_src[p] = e;
}

// ---- Kernel: per-edge prep — R0 VERBATIM minus the cnt atomic.
// rT rows: 0..31 xs*y0 | 32..47 vdot*inv3 | 48..79 xs | 80..127 xv*y0
__global__ void k_prep(const float* __restrict__ x, const float* __restrict__ edge_attr,
                       const float* __restrict__ Yij, const int* __restrict__ edge_index,
                       unsigned short* __restrict__ emb, float* __restrict__ rT) {
    int e = blockIdx.x * 256 + threadIdx.x;
    if (e >= E_EDGES) return;
    int dst = edge_index[e];
    int src = edge_index[E_EDGES + e];
    f32x4 y = *(const f32x4*)(Yij + 4 * (long)e);
    float y0 = y.x, y1a = y.y, y1b = y.z, y1c = y.w;
    const float* xd = x + (long)dst * 80;
    const float* xs = x + (long)src * 80;
    const float* ea = edge_attr + (long)e * 64;

    ushort8* embp = (ushort8*)(emb + (long)e * 128);

    float xsv[80];
#pragma unroll
    for (int i = 0; i < 80; i += 4) {
        f32x4 v = *(const f32x4*)(xs + i);
        xsv[i] = v.x; xsv[i + 1] = v.y; xsv[i + 2] = v.z; xsv[i + 3] = v.w;
    }
#pragma unroll
    for (int cb = 0; cb < 4; ++cb) {
        f32x4 a = *(const f32x4*)(xd + cb * 8);
        f32x4 b = *(const f32x4*)(xd + cb * 8 + 4);
        embp[cb] = pack8(a, b);
    }
#pragma unroll
    for (int cb = 0; cb < 4; ++cb) {
        f32x4 a, b;
        a.x = xsv[cb * 8 + 0]; a.y = xsv[cb * 8 + 1]; a.z = xsv[cb * 8 + 2]; a.w = xsv[cb * 8 + 3];
        b.x = xsv[cb * 8 + 4]; b.y = xsv[cb * 8 + 5]; b.z = xsv[cb * 8 + 6]; b.w = xsv[cb * 8 + 7];
        embp[4 + cb] = pack8(a, b);
    }
#pragma unroll
    for (int cb = 0; cb < 8; ++cb) {
        f32x4 a = *(const f32x4*)(ea + cb * 8);
        f32x4 b = *(const f32x4*)(ea + cb * 8 + 4);
        embp[8 + cb] = pack8(a, b);
    }
#pragma unroll
    for (int u = 0; u < 32; ++u) rT[(long)u * E_EDGES + e] = xsv[u] * y0;
#pragma unroll
    for (int u = 0; u < 16; ++u)
        rT[(long)(32 + u) * E_EDGES + e] =
            (xsv[32 + 3 * u] * y1a + xsv[33 + 3 * u] * y1b + xsv[34 + 3 * u] * y1c) * INV_SQRT3;
#pragma unroll
    for (int u = 0; u < 32; ++u) rT[(long)(48 + u) * E_EDGES + e] = xsv[u];
#pragma unroll
    for (int j = 0; j < 48; ++j) rT[(long)(80 + j) * E_EDGES + e] = xsv[32 + j] * y0;
}

// ---- Kernel: fused GEMM + u-contraction — R0 loop VERBATIM, original edge
// order. ONLY change: epilogue stores the per-edge message to msg[e][96]
// (plain coalesced 64B-line stores, idempotent, no RMW) instead of atomics.
// Reduction happens in k_nodesum via the sorted edge lists.
__global__ __launch_bounds__(256, 4) void k_gemm(
    const unsigned short* __restrict__ emb, const unsigned short* __restrict__ Bt,
    const float* __restrict__ rT, const float* __restrict__ Yij,
    float* __restrict__ msg) {
    const int lane = threadIdx.x & 63;
    const int wave = threadIdx.x >> 6;
    long e0 = (long)blockIdx.x * 128 + (long)wave * 32;
    const bool dup = (e0 + 32 > E_EDGES);
    if (dup) e0 = E_EDGES - 32;
    const int col = lane & 15, quad = lane >> 4;

    __shared__ __align__(16) char lds[2][16384];

    // A fragments, register-resident for the whole sweep
    bfrag A[2][4];
#pragma unroll
    for (int s = 0; s < 2; ++s) {
        const unsigned short* ap = emb + (e0 + s * 16 + col) * 128 + quad * 8;
#pragma unroll
        for (int kb = 0; kb < 4; ++kb) A[s][kb] = *(const bfrag*)(ap + kb * 32);
    }

    auto stage = [&](int ci) {
        const char* g = (const char*)Bt + (size_t)ci * 16384 + wave * 4096 + lane * 16;
        char* l = &lds[ci & 1][wave * 4096];
#pragma unroll
        for (int j = 0; j < 4; ++j)
            __builtin_amdgcn_global_load_lds(
                (const __attribute__((address_space(1))) unsigned int*)(g + j * 1024),
                (__attribute__((address_space(3))) unsigned int*)(l + j * 1024), 16, 0, 0);
    };

    f32x4 z = {0.f, 0.f, 0.f, 0.f};
    f32x4 acc_s0[2] = {z, z}, acc_s1[2] = {z, z}, acc_g[2] = {z, z}, acc_t5[2] = {z, z};
    f32x4 acc_v[2][3] = {{z, z, z}, {z, z, z}};

    const float* rbase = rT + e0 + quad * 4;
    auto loadw = [&](int r, f32x4& a, f32x4& b) {
        const float* p = rbase + (long)r * E_EDGES;
        a = *(const f32x4*)(p);
        b = *(const f32x4*)(p + 16);
    };

    auto tile = [&](const char* lt, f32x4& c0, f32x4& c1) {
        bfrag B0 = *(const bfrag*)(lt + lane * 16);
        bfrag B1 = *(const bfrag*)(lt + lane * 16 + 1024);
        bfrag B2 = *(const bfrag*)(lt + lane * 16 + 2048);
        bfrag B3 = *(const bfrag*)(lt + lane * 16 + 3072);
        c0 = z; c1 = z;
        c0 = __builtin_amdgcn_mfma_f32_16x16x32_bf16(A[0][0], B0, c0, 0, 0, 0);
        c1 = __builtin_amdgcn_mfma_f32_16x16x32_bf16(A[1][0], B0, c1, 0, 0, 0);
        c0 = __builtin_amdgcn_mfma_f32_16x16x32_bf16(A[0][1], B1, c0, 0, 0, 0);
        c1 = __builtin_amdgcn_mfma_f32_16x16x32_bf16(A[1][1], B1, c1, 0, 0, 0);
        c0 = __builtin_amdgcn_mfma_f32_16x16x32_bf16(A[0][2], B2, c0, 0, 0, 0);
        c1 = __builtin_amdgcn_mfma_f32_16x16x32_bf16(A[1][2], B2, c1, 0, 0, 0);
        c0 = __builtin_amdgcn_mfma_f32_16x16x32_bf16(A[0][3], B3, c0, 0, 0, 0);
        c1 = __builtin_amdgcn_mfma_f32_16x16x32_bf16(A[1][3], B3, c1, 0, 0, 0);
    };

    stage(0);
    int cidx = 0;
    auto nextbuf = [&]() -> const char* {
        __syncthreads();
        if (cidx + 1 < 48) stage(cidx + 1);
        const char* b = lds[cidx & 1];
        ++cidx;
        return b;
    };

    f32x4 c0, c1;

    // W1: chunks 0..15, rows 2j,2j+1 -> acc_s
    {
        f32x4 p0a, p0b, p1a, p1b;
        loadw(0, p0a, p0b); loadw(1, p1a, p1b);
#pragma unroll 1
        for (int j = 0; j < 16; ++j) {
            const char* buf = nextbuf();
            f32x4 w0a = p0a, w0b = p0b, w1a = p1a, w1b = p1b;
            int nr = (j < 15) ? (2 * j + 2) : 0;
            loadw(nr, p0a, p0b); loadw(nr + 1, p1a, p1b);
            tile(buf,         c0, c1); acc_s0[0] += c0 * w0a; acc_s0[1] += c1 * w0b;
            tile(buf + 4096,  c0, c1); acc_s1[0] += c0 * w0a; acc_s1[1] += c1 * w0b;
            tile(buf + 8192,  c0, c1); acc_s0[0] += c0 * w1a; acc_s0[1] += c1 * w1b;
            tile(buf + 12288, c0, c1); acc_s1[0] += c0 * w1a; acc_s1[1] += c1 * w1b;
        }
    }
    // W2: chunks 16..23, rows 4j..4j+3 -> acc_g
    {
        f32x4 pa[4], pb[4];
#pragma unroll
        for (int i = 0; i < 4; ++i) loadw(i, pa[i], pb[i]);
#pragma unroll 1
        for (int j = 0; j < 8; ++j) {
            const char* buf = nextbuf();
            f32x4 wa[4], wb[4];
#pragma unroll
            for (int i = 0; i < 4; ++i) { wa[i] = pa[i]; wb[i] = pb[i]; }
            int nr = (j < 7) ? (4 * j + 4) : 0;
#pragma unroll
            for (int i = 0; i < 4; ++i) loadw(nr + i, pa[i], pb[i]);
#pragma unroll
            for (int i = 0; i < 4; ++i) {
                tile(buf + i * 4096, c0, c1);
                acc_g[0] += c0 * wa[i]; acc_g[1] += c1 * wb[i];
            }
        }
    }
    // W3: chunks 24..31, rows 32+2j,33+2j -> acc_s
    {
        f32x4 p0a, p0b, p1a, p1b;
        loadw(32, p0a, p0b); loadw(33, p1a, p1b);
#pragma unroll 1
        for (int j = 0; j < 8; ++j) {
            const char* buf = nextbuf();
            f32x4 w0a = p0a, w0b = p0b, w1a = p1a, w1b = p1b;
            int nr = (j < 7) ? (32 + 2 * j + 2) : 32;
            loadw(nr, p0a, p0b); loadw(nr + 1, p1a, p1b);
            tile(buf,         c0, c1); acc_s0[0] += c0 * w0a; acc_s0[1] += c1 * w0b;
            tile(buf + 4096,  c0, c1); acc_s1[0] += c0 * w0a; acc_s1[1] += c1 * w0b;
            tile(buf + 8192,  c0, c1); acc_s0[0] += c0 * w1a; acc_s0[1] += c1 * w1b;
            tile(buf + 12288, c0, c1); acc_s1[0] += c0 * w1a; acc_s1[1] += c1 * w1b;
        }
    }
    // W4: chunks 32..35, rows 32+4j+i -> acc_g
    {
        f32x4 pa[4], pb[4];
#pragma unroll
        for (int i = 0; i < 4; ++i) loadw(32 + i, pa[i], pb[i]);
#pragma unroll 1
        for (int j = 0; j < 4; ++j) {
            const char* buf = nextbuf();
            f32x4 wa[4], wb[4];
#pragma unroll
            for (int i = 0; i < 4; ++i) { wa[i] = pa[i]; wb[i] = pb[i]; }
            int nr = (j < 3) ? (32 + 4 * j + 4) : 32;
#pragma unroll
            for (int i = 0; i < 4; ++i) loadw(nr + i, pa[i], pb[i]);
#pragma unroll
            for (int i = 0; i < 4; ++i) {
                tile(buf + i * 4096, c0, c1);
                acc_g[0] += c0 * wa[i]; acc_g[1] += c1 * wb[i];
            }
        }
    }
    // W5: chunks 36..43, rows 48+4j+i -> acc_t5
    {
        f32x4 pa[4], pb[4];
#pragma unroll
        for (int i = 0; i < 4; ++i) loadw(48 + i, pa[i], pb[i]);
#pragma unroll 1
        for (int j = 0; j < 8; ++j) {
            const char* buf = nextbuf();
            f32x4 wa[4], wb[4];
#pragma unroll
            for (int i = 0; i < 4; ++i) { wa[i] = pa[i]; wb[i] = pb[i]; }
            int nr = (j < 7) ? (48 + 4 * j + 4) : 48;
#pragma unroll
            for (int i = 0; i < 4; ++i) loadw(nr + i, pa[i], pb[i]);
#pragma unroll
            for (int i = 0; i < 4; ++i) {
                tile(buf + i * 4096, c0, c1);
                acc_t5[0] += c0 * wa[i]; acc_t5[1] += c1 * wb[i];
            }
        }
    }
    // W6: chunks 44..47, u=4j+i, rows 80+3u+k -> acc_v[k]
    {
        f32x4 va[3], vb[3];
#pragma unroll
        for (int k = 0; k < 3; ++k) loadw(80 + k, va[k], vb[k]);
#pragma unroll 1
        for (int j = 0; j < 4; ++j) {
            const char* buf = nextbuf();
#pragma unroll
            for (int i = 0; i < 4; ++i) {
                f32x4 wa[3], wb[3];
#pragma unroll
                for (int k = 0; k < 3; ++k) { wa[k] = va[k]; wb[k] = vb[k]; }
                int un = 4 * j + i + 1; if (un > 15) un = 0;
#pragma unroll
                for (int k = 0; k < 3; ++k) loadw(80 + 3 * un + k, va[k], vb[k]);
                tile(buf + i * 4096, c0, c1);
#pragma unroll
                for (int k = 0; k < 3; ++k) {
                    acc_v[0][k] += c0 * wa[k];
                    acc_v[1][k] += c1 * wb[k];
                }
            }
        }
    }

    if (dup) return;
    // Epilogue: scale + COALESCED STORES into msg[e][96] (no atomics).
    // Per (s,r): the 16 lanes of each quad write one contiguous 64B line.
#pragma unroll
    for (int s = 0; s < 2; ++s) {
        long eb = e0 + s * 16 + quad * 4;
#pragma unroll
        for (int r = 0; r < 4; ++r) {
            long e = eb + r;
            float* base = msg + e * 96;
            float y1a = Yij[4 * e + 1], y1b = Yij[4 * e + 2], y1c = Yij[4 * e + 3];
            base[col]            = N_0E_C * acc_s0[s][r];
            base[col + 16]       = N_0E_C * acc_s1[s][r];
            base[32 + col]       = N_0E_C * acc_g[s][r];
            float t5 = acc_t5[s][r];
            base[48 + col * 3 + 0] = NV_C * (t5 * y1a + acc_v[s][0][r]);
            base[48 + col * 3 + 1] = NV_C * (t5 * y1b + acc_v[s][1][r]);
            base[48 + col * 3 + 2] = NV_C * (t5 * y1c + acc_v[s][2][r]);
        }
    }
}

// ---- Kernel: per-node gather-sum over sorted edge list + mean, relu-gate,
// residual (absorbs old k_final). One block per node, 128 threads.
__global__ __launch_bounds__(128) void k_nodesum(
    const float* __restrict__ msg, const int* __restrict__ perm_src,
    const int* __restrict__ offs, const float* __restrict__ x,
    float* __restrict__ out) {
    int n = blockIdx.x;
    int t = threadIdx.x;
    int lo = offs[n], hi = offs[n + 1];
    float s = 0.0f;
    if (t < 96) {
        for (int i = lo; i < hi; ++i) {
            int p = perm_src[i];
            s += msg[(long)p * 96 + t];
        }
    }
    float inv = 1.0f / fmaxf((float)(hi - lo), 1.0f);
    __shared__ float sm[96];
    if (t < 96) sm[t] = s * inv;
    __syncthreads();
    if (t < 80) {
        float val;
        if (t < 32) {
            val = SQRT2_C * fmaxf(sm[t], 0.0f);
        } else {
            int j = t - 32;
            int w = j / 3;
            float g = SQRT2_C * fmaxf(sm[32 + w], 0.0f);
            val = sm[48 + j] * g;
        }
        out[(long)n * 80 + t] = x[(long)n * 80 + t] + val;
    }
}

extern "C" void kernel_launch(void* const* d_in, const int* in_sizes, int n_in,
                              void* d_out, int out_size, void* d_ws, size_t ws_size,
                              hipStream_t stream) {
    const float* x         = (const float*)d_in[0];
    const float* edge_attr = (const float*)d_in[1];
    const float* Yij       = (const float*)d_in[2];
    const int*   edge_index= (const int*)d_in[3];
    const float* w_emb     = (const float*)d_in[4];
    float* out = (float*)d_out;

    char* ws = (char*)d_ws;
    size_t off = 0;
    unsigned short* emb = (unsigned short*)(ws + off); off += (size_t)E_EDGES * 128 * 2;
    unsigned short* Bt  = (unsigned short*)(ws + off); off += (size_t)3072 * 128 * 2;
    off = (off + 255) & ~(size_t)255;
    float* rT      = (float*)(ws + off); off += (size_t)128 * E_EDGES * 4;
    float* msg     = (float*)(ws + off); off += (size_t)E_EDGES * 96 * 4;
    int*   perm_src= (int*)(ws + off);   off += (size_t)E_EDGES * 4;
    int*   offs    = (int*)(ws + off);   off += (size_t)(NUM_NODES + 1) * 4;
    size_t zoff = off;
    int*   cnt     = (int*)(ws + off);   off += (size_t)NUM_NODES * 4;
    int*   cursor  = (int*)(ws + off);   off += (size_t)NUM_NODES * 4;

    hipMemsetAsync(ws + zoff, 0, (size_t)NUM_NODES * 2 * 4, stream);
    k_wt     <<<(3072 * 128 + 255) / 256, 256, 0, stream>>>(w_emb, Bt);
    k_count  <<<(E_EDGES + 255) / 256, 256, 0, stream>>>(edge_index, cnt);
    k_scan   <<<1, 256, 0, stream>>>(cnt, offs);
    k_scatter<<<(E_EDGES + 255) / 256, 256, 0, stream>>>(edge_index, offs, cursor, perm_src);
    k_prep   <<<(E_EDGES + 255) / 256, 256, 0, stream>>>(x, edge_attr, Yij, edge_index, emb, rT);
    k_gemm   <<<(E_EDGES + 127) / 128, 256, 0, stream>>>(emb, Bt, rT, Yij, msg);
    k_nodesum<<<NUM_NODES, 128, 0, stream>>>(msg, perm_src, offs, x, out);
}

// Round 7
// 320.283 us; speedup vs baseline: 1.6857x; 1.0519x over previous
//
#include <hip/hip_runtime.h>
#include <hip/hip_bf16.h>

#define E_EDGES 120000
#define NUM_NODES 12000

typedef __attribute__((ext_vector_type(8))) short bfrag;          // 8 bf16
typedef __attribute__((ext_vector_type(8))) unsigned short ushort8;
typedef __attribute__((ext_vector_type(4))) float f32x4;

#define INV_SQRT3 0.57735026918962576f
#define SQRT2_C   1.41421356237309515f
#define N_0E_C    0.14433756729740643f   /* 1/sqrt(48) */
#define NV_C      0.14433756729740643f   /* sqrt(3/48)*1/sqrt(3) = 1/sqrt(48) */
#define WSCALE    0.08838834764831845f   /* 1/sqrt(128) */

__device__ __forceinline__ unsigned short f2bf(float f) {
    union { float f; unsigned int u; } v; v.f = f;
    unsigned int r = v.u + 0x7fffu + ((v.u >> 16) & 1u);
    return (unsigned short)(r >> 16);
}

__device__ __forceinline__ ushort8 pack8(f32x4 a, f32x4 b) {
    ushort8 o;
    o[0] = f2bf(a.x); o[1] = f2bf(a.y); o[2] = f2bf(a.z); o[3] = f2bf(a.w);
    o[4] = f2bf(b.x); o[5] = f2bf(b.y); o[6] = f2bf(b.z); o[7] = f2bf(b.w);
    return o;
}

// ---- Kernel: w_emb (128 x 3072) -> Bt in fragment-consumption order.
__global__ void k_wt(const float* __restrict__ w_emb, unsigned short* __restrict__ Bt) {
    int o = blockIdx.x * 256 + threadIdx.x;
    if (o >= 3072 * 128) return;
    int t = o >> 11;
    int c = (o >> 3) & 255;
    int j = o & 7;
    int kb = c >> 6;
    int quad = (c >> 4) & 3;
    int col = c & 15;
    int k = kb * 32 + quad * 8 + j;
    int n = t * 16 + col;
    Bt[o] = f2bf(w_emb[k * 3072 + n] * WSCALE);
}

// ---- Counting sort by dst (for the REDUCTION pass only): count -> scan -> scatter
__global__ void k_count(const int* __restrict__ edge_index, int* __restrict__ cnt) {
    int e = blockIdx.x * 256 + threadIdx.x;
    if (e >= E_EDGES) return;
    atomicAdd(cnt + edge_index[e], 1);
}

__global__ void k_scan(const int* __restrict__ cnt, int* __restrict__ offs) {
    __shared__ int psum[256];
    int t = threadIdx.x;
    const int SEG = (NUM_NODES + 255) / 256;  // 47
    int lo = t * SEG;
    int hi = lo + SEG; if (hi > NUM_NODES) hi = NUM_NODES;
    int s = 0;
    for (int i = lo; i < hi; ++i) s += cnt[i];
    psum[t] = s;
    __syncthreads();
    if (t == 0) {
        int acc = 0;
        for (int i = 0; i < 256; ++i) { int v = psum[i]; psum[i] = acc; acc += v; }
    }
    __syncthreads();
    int acc = psum[t];
    for (int i = lo; i < hi; ++i) { offs[i] = acc; acc += cnt[i]; }
    if (t == 255) offs[NUM_NODES] = acc;   // == E_EDGES
}

__global__ void k_scatter(const int* __restrict__ edge_index, const int* __restrict__ offs,
                          int* __restrict__ cursor, int* __restrict__ perm_src) {
    int e = blockIdx.x * 256 + threadIdx.x;
    if (e >= E_EDGES) return;
    int d = edge_index[e];
    int p = offs[d] + atomicAdd(cursor + d, 1);
    perm_src[p] = e;
}

// ---- Kernel: per-edge prep, WAVE-SLICED 5x.
// R6's k_prep was 1876 waves (1.8/SIMD) with ~100 VGPRs and 128 scalar
// stores/thread -> latency-bound ~115us. Now: 320-thread blocks (5 waves),
// block handles 64 edges, each WAVE owns one output slice for those edges
// (lane = edge -> all stores stay full-line coalesced):
//   wave 0: rT rows  0..31  = xs[u]*y0
//   wave 1: rT rows 32..47  = vdot*inv3 ; rows 48..63 = xs[0..15]
//   wave 2: rT rows 64..79  = xs[16..31]; rows 80..95 = xv[0..15]*y0
//   wave 3: rT rows 96..127 = xv[16..47]*y0
//   wave 4: emb bf16 pack [xd(32) | xs(32) | ea(64)]
// 9375 waves total, ~10 VGPR/thread. x (3.8MB) is L2-resident; duplicate
// gathers across waves are cheap.
__global__ __launch_bounds__(320) void k_prep(
    const float* __restrict__ x, const float* __restrict__ edge_attr,
    const float* __restrict__ Yij, const int* __restrict__ edge_index,
    unsigned short* __restrict__ emb, float* __restrict__ rT) {
    const int wid = threadIdx.x >> 6;
    const int lane = threadIdx.x & 63;
    const long e = (long)blockIdx.x * 64 + lane;   // 1875*64 == 120000 exact
    const int src = edge_index[E_EDGES + e];
    const float* xs = x + (long)src * 80;
    const f32x4 y = *(const f32x4*)(Yij + 4 * e);

    if (wid == 4) {
        const int dst = edge_index[e];
        const float* xd = x + (long)dst * 80;
        const float* ea = edge_attr + (long)e * 64;
        ushort8* embp = (ushort8*)(emb + (long)e * 128);
#pragma unroll
        for (int cb = 0; cb < 4; ++cb)
            embp[cb] = pack8(*(const f32x4*)(xd + cb * 8), *(const f32x4*)(xd + cb * 8 + 4));
#pragma unroll
        for (int cb = 0; cb < 4; ++cb)
            embp[4 + cb] = pack8(*(const f32x4*)(xs + cb * 8), *(const f32x4*)(xs + cb * 8 + 4));
#pragma unroll
        for (int cb = 0; cb < 8; ++cb)
            embp[8 + cb] = pack8(*(const f32x4*)(ea + cb * 8), *(const f32x4*)(ea + cb * 8 + 4));
    } else if (wid == 0) {
        const float y0 = y.x;
#pragma unroll
        for (int i = 0; i < 8; ++i) {
            f32x4 v = *(const f32x4*)(xs + i * 4);
            rT[(long)(4 * i + 0) * E_EDGES + e] = v.x * y0;
            rT[(long)(4 * i + 1) * E_EDGES + e] = v.y * y0;
            rT[(long)(4 * i + 2) * E_EDGES + e] = v.z * y0;
            rT[(long)(4 * i + 3) * E_EDGES + e] = v.w * y0;
        }
    } else if (wid == 1) {
        const float y1a = y.y, y1b = y.z, y1c = y.w;
        float xv[48];
#pragma unroll
        for (int i = 0; i < 12; ++i) {
            f32x4 v = *(const f32x4*)(xs + 32 + i * 4);
            xv[4 * i] = v.x; xv[4 * i + 1] = v.y; xv[4 * i + 2] = v.z; xv[4 * i + 3] = v.w;
        }
#pragma unroll
        for (int u = 0; u < 16; ++u)
            rT[(long)(32 + u) * E_EDGES + e] =
                (xv[3 * u] * y1a + xv[3 * u + 1] * y1b + xv[3 * u + 2] * y1c) * INV_SQRT3;
#pragma unroll
        for (int i = 0; i < 4; ++i) {
            f32x4 v = *(const f32x4*)(xs + i * 4);
            rT[(long)(48 + 4 * i + 0) * E_EDGES + e] = v.x;
            rT[(long)(48 + 4 * i + 1) * E_EDGES + e] = v.y;
            rT[(long)(48 + 4 * i + 2) * E_EDGES + e] = v.z;
            rT[(long)(48 + 4 * i + 3) * E_EDGES + e] = v.w;
        }
    } else if (wid == 2) {
        const float y0 = y.x;
#pragma unroll
        for (int i = 0; i < 4; ++i) {
            f32x4 v = *(const f32x4*)(xs + 16 + i * 4);
            rT[(long)(64 + 4 * i + 0) * E_EDGES + e] = v.x;
            rT[(long)(64 + 4 * i + 1) * E_EDGES + e] = v.y;
            rT[(long)(64 + 4 * i + 2) * E_EDGES + e] = v.z;
            rT[(long)(64 + 4 * i + 3) * E_EDGES + e] = v.w;
        }
#pragma unroll
        for (int i = 0; i < 4; ++i) {
            f32x4 v = *(const f32x4*)(xs + 32 + i * 4);
            rT[(long)(80 + 4 * i + 0) * E_EDGES + e] = v.x * y0;
            rT[(long)(80 + 4 * i + 1) * E_EDGES + e] = v.y * y0;
            rT[(long)(80 + 4 * i + 2) * E_EDGES + e] = v.z * y0;
            rT[(long)(80 + 4 * i + 3) * E_EDGES + e] = v.w * y0;
        }
    } else {  // wid == 3
        const float y0 = y.x;
#pragma unroll
        for (int i = 0; i < 8; ++i) {
            f32x4 v = *(const f32x4*)(xs + 48 + i * 4);
            rT[(long)(96 + 4 * i + 0) * E_EDGES + e] = v.x * y0;
            rT[(long)(96 + 4 * i + 1) * E_EDGES + e] = v.y * y0;
            rT[(long)(96 + 4 * i + 2) * E_EDGES + e] = v.z * y0;
            rT[(long)(96 + 4 * i + 3) * E_EDGES + e] = v.w * y0;
        }
    }
}

// ---- Kernel: fused GEMM + u-contraction — R6 VERBATIM (measured 150.6us).
__global__ __launch_bounds__(256, 4) void k_gemm(
    const unsigned short* __restrict__ emb, const unsigned short* __restrict__ Bt,
    const float* __restrict__ rT, const float* __restrict__ Yij,
    float* __restrict__ msg) {
    const int lane = threadIdx.x & 63;
    const int wave = threadIdx.x >> 6;
    long e0 = (long)blockIdx.x * 128 + (long)wave * 32;
    const bool dup = (e0 + 32 > E_EDGES);
    if (dup) e0 = E_EDGES - 32;
    const int col = lane & 15, quad = lane >> 4;

    __shared__ __align__(16) char lds[2][16384];

    // A fragments, register-resident for the whole sweep
    bfrag A[2][4];
#pragma unroll
    for (int s = 0; s < 2; ++s) {
        const unsigned short* ap = emb + (e0 + s * 16 + col) * 128 + quad * 8;
#pragma unroll
        for (int kb = 0; kb < 4; ++kb) A[s][kb] = *(const bfrag*)(ap + kb * 32);
    }

    auto stage = [&](int ci) {
        const char* g = (const char*)Bt + (size_t)ci * 16384 + wave * 4096 + lane * 16;
        char* l = &lds[ci & 1][wave * 4096];
#pragma unroll
        for (int j = 0; j < 4; ++j)
            __builtin_amdgcn_global_load_lds(
                (const __attribute__((address_space(1))) unsigned int*)(g + j * 1024),
                (__attribute__((address_space(3))) unsigned int*)(l + j * 1024), 16, 0, 0);
    };

    f32x4 z = {0.f, 0.f, 0.f, 0.f};
    f32x4 acc_s0[2] = {z, z}, acc_s1[2] = {z, z}, acc_g[2] = {z, z}, acc_t5[2] = {z, z};
    f32x4 acc_v[2][3] = {{z, z, z}, {z, z, z}};

    const float* rbase = rT + e0 + quad * 4;
    auto loadw = [&](int r, f32x4& a, f32x4& b) {
        const float* p = rbase + (long)r * E_EDGES;
        a = *(const f32x4*)(p);
        b = *(const f32x4*)(p + 16);
    };

    auto tile = [&](const char* lt, f32x4& c0, f32x4& c1) {
        bfrag B0 = *(const bfrag*)(lt + lane * 16);
        bfrag B1 = *(const bfrag*)(lt + lane * 16 + 1024);
        bfrag B2 = *(const bfrag*)(lt + lane * 16 + 2048);
        bfrag B3 = *(const bfrag*)(lt + lane * 16 + 3072);
        c0 = z; c1 = z;
        c0 = __builtin_amdgcn_mfma_f32_16x16x32_bf16(A[0][0], B0, c0, 0, 0, 0);
        c1 = __builtin_amdgcn_mfma_f32_16x16x32_bf16(A[1][0], B0, c1, 0, 0, 0);
        c0 = __builtin_amdgcn_mfma_f32_16x16x32_bf16(A[0][1], B1, c0, 0, 0, 0);
        c1 = __builtin_amdgcn_mfma_f32_16x16x32_bf16(A[1][1], B1, c1, 0, 0, 0);
        c0 = __builtin_amdgcn_mfma_f32_16x16x32_bf16(A[0][2], B2, c0, 0, 0, 0);
        c1 = __builtin_amdgcn_mfma_f32_16x16x32_bf16(A[1][2], B2, c1, 0, 0, 0);
        c0 = __builtin_amdgcn_mfma_f32_16x16x32_bf16(A[0][3], B3, c0, 0, 0, 0);
        c1 = __builtin_amdgcn_mfma_f32_16x16x32_bf16(A[1][3], B3, c1, 0, 0, 0);
    };

    stage(0);
    int cidx = 0;
    auto nextbuf = [&]() -> const char* {
        __syncthreads();
        if (cidx + 1 < 48) stage(cidx + 1);
        const char* b = lds[cidx & 1];
        ++cidx;
        return b;
    };

    f32x4 c0, c1;

    // W1: chunks 0..15, rows 2j,2j+1 -> acc_s
    {
        f32x4 p0a, p0b, p1a, p1b;
        loadw(0, p0a, p0b); loadw(1, p1a, p1b);
#pragma unroll 1
        for (int j = 0; j < 16; ++j) {
            const char* buf = nextbuf();
            f32x4 w0a = p0a, w0b = p0b, w1a = p1a, w1b = p1b;
            int nr = (j < 15) ? (2 * j + 2) : 0;
            loadw(nr, p0a, p0b); loadw(nr + 1, p1a, p1b);
            tile(buf,         c0, c1); acc_s0[0] += c0 * w0a; acc_s0[1] += c1 * w0b;
            tile(buf + 4096,  c0, c1); acc_s1[0] += c0 * w0a; acc_s1[1] += c1 * w0b;
            tile(buf + 8192,  c0, c1); acc_s0[0] += c0 * w1a; acc_s0[1] += c1 * w1b;
            tile(buf + 12288, c0, c1); acc_s1[0] += c0 * w1a; acc_s1[1] += c1 * w1b;
        }
    }
    // W2: chunks 16..23, rows 4j..4j+3 -> acc_g
    {
        f32x4 pa[4], pb[4];
#pragma unroll
        for (int i = 0; i < 4; ++i) loadw(i, pa[i], pb[i]);
#pragma unroll 1
        for (int j = 0; j < 8; ++j) {
            const char* buf = nextbuf();
            f32x4 wa[4], wb[4];
#pragma unroll
            for (int i = 0; i < 4; ++i) { wa[i] = pa[i]; wb[i] = pb[i]; }
            int nr = (j < 7) ? (4 * j + 4) : 0;
#pragma unroll
            for (int i = 0; i < 4; ++i) loadw(nr + i, pa[i], pb[i]);
#pragma unroll
            for (int i = 0; i < 4; ++i) {
                tile(buf + i * 4096, c0, c1);
                acc_g[0] += c0 * wa[i]; acc_g[1] += c1 * wb[i];
            }
        }
    }
    // W3: chunks 24..31, rows 32+2j,33+2j -> acc_s
    {
        f32x4 p0a, p0b, p1a, p1b;
        loadw(32, p0a, p0b); loadw(33, p1a, p1b);
#pragma unroll 1
        for (int j = 0; j < 8; ++j) {
            const char* buf = nextbuf();
            f32x4 w0a = p0a, w0b = p0b, w1a = p1a, w1b = p1b;
            int nr = (j < 7) ? (32 + 2 * j + 2) : 32;
            loadw(nr, p0a, p0b); loadw(nr + 1, p1a, p1b);
            tile(buf,         c0, c1); acc_s0[0] += c0 * w0a; acc_s0[1] += c1 * w0b;
            tile(buf + 4096,  c0, c1); acc_s1[0] += c0 * w0a; acc_s1[1] += c1 * w0b;
            tile(buf + 8192,  c0, c1); acc_s0[0] += c0 * w1a; acc_s0[1] += c1 * w1b;
            tile(buf + 12288, c0, c1); acc_s1[0] += c0 * w1a; acc_s1[1] += c1 * w1b;
        }
    }
    // W4: chunks 32..35, rows 32+4j+i -> acc_g
    {
        f32x4 pa[4], pb[4];
#pragma unroll
        for (int i = 0; i < 4; ++i) loadw(32 + i, pa[i], pb[i]);
#pragma unroll 1
        for (int j = 0; j < 4; ++j) {
            const char* buf = nextbuf();
            f32x4 wa[4], wb[4];
#pragma unroll
            for (int i = 0; i < 4; ++i) { wa[i] = pa[i]; wb[i] = pb[i]; }
            int nr = (j < 3) ? (32 + 4 * j + 4) : 32;
#pragma unroll
            for (int i = 0; i < 4; ++i) loadw(nr + i, pa[i], pb[i]);
#pragma unroll
            for (int i = 0; i < 4; ++i) {
                tile(buf + i * 4096, c0, c1);
                acc_g[0] += c0 * wa[i]; acc_g[1] += c1 * wb[i];
            }
        }
    }
    // W5: chunks 36..43, rows 48+4j+i -> acc_t5
    {
        f32x4 pa[4], pb[4];
#pragma unroll
        for (int i = 0; i < 4; ++i) loadw(48 + i, pa[i], pb[i]);
#pragma unroll 1
        for (int j = 0; j < 8; ++j) {
            const char* buf = nextbuf();
            f32x4 wa[4], wb[4];
#pragma unroll
            for (int i = 0; i < 4; ++i) { wa[i] = pa[i]; wb[i] = pb[i]; }
            int nr = (j < 7) ? (48 + 4 * j + 4) : 48;
#pragma unroll
            for (int i = 0; i < 4; ++i) loadw(nr + i, pa[i], pb[i]);
#pragma unroll
            for (int i = 0; i < 4; ++i) {
                tile(buf + i * 4096, c0, c1);
                acc_t5[0] += c0 * wa[i]; acc_t5[1] += c1 * wb[i];
            }
        }
    }
    // W6: chunks 44..47, u=4j+i, rows 80+3u+k -> acc_v[k]
    {
        f32x4 va[3], vb[3];
#pragma unroll
        for (int k = 0; k < 3; ++k) loadw(80 + k, va[k], vb[k]);
#pragma unroll 1
        for (int j = 0; j < 4; ++j) {
            const char* buf = nextbuf();
#pragma unroll
            for (int i = 0; i < 4; ++i) {
                f32x4 wa[3], wb[3];
#pragma unroll
                for (int k = 0; k < 3; ++k) { wa[k] = va[k]; wb[k] = vb[k]; }
                int un = 4 * j + i + 1; if (un > 15) un = 0;
#pragma unroll
                for (int k = 0; k < 3; ++k) loadw(80 + 3 * un + k, va[k], vb[k]);
                tile(buf + i * 4096, c0, c1);
#pragma unroll
                for (int k = 0; k < 3; ++k) {
                    acc_v[0][k] += c0 * wa[k];
                    acc_v[1][k] += c1 * wb[k];
                }
            }
        }
    }

    if (dup) return;
    // Epilogue: scale + COALESCED STORES into msg[e][96] (no atomics).
#pragma unroll
    for (int s = 0; s < 2; ++s) {
        long eb = e0 + s * 16 + quad * 4;
#pragma unroll
        for (int r = 0; r < 4; ++r) {
            long e = eb + r;
            float* base = msg + e * 96;
            float y1a = Yij[4 * e + 1], y1b = Yij[4 * e + 2], y1c = Yij[4 * e + 3];
            base[col]            = N_0E_C * acc_s0[s][r];
            base[col + 16]       = N_0E_C * acc_s1[s][r];
            base[32 + col]       = N_0E_C * acc_g[s][r];
            float t5 = acc_t5[s][r];
            base[48 + col * 3 + 0] = NV_C * (t5 * y1a + acc_v[s][0][r]);
            base[48 + col * 3 + 1] = NV_C * (t5 * y1b + acc_v[s][1][r]);
            base[48 + col * 3 + 2] = NV_C * (t5 * y1c + acc_v[s][2][r]);
        }
    }
}

// ---- Kernel: per-node gather-sum over sorted edge list + mean, relu-gate,
// residual. One block per node, 128 threads.
__global__ __launch_bounds__(128) void k_nodesum(
    const float* __restrict__ msg, const int* __restrict__ perm_src,
    const int* __restrict__ offs, const float* __restrict__ x,
    float* __restrict__ out) {
    int n = blockIdx.x;
    int t = threadIdx.x;
    int lo = offs[n], hi = offs[n + 1];
    float s = 0.0f;
    if (t < 96) {
        for (int i = lo; i < hi; ++i) {
            int p = perm_src[i];
            s += msg[(long)p * 96 + t];
        }
    }
    float inv = 1.0f / fmaxf((float)(hi - lo), 1.0f);
    __shared__ float sm[96];
    if (t < 96) sm[t] = s * inv;
    __syncthreads();
    if (t < 80) {
        float val;
        if (t < 32) {
            val = SQRT2_C * fmaxf(sm[t], 0.0f);
        } else {
            int j = t - 32;
            int w = j / 3;
            float g = SQRT2_C * fmaxf(sm[32 + w], 0.0f);
            val = sm[48 + j] * g;
        }
        out[(long)n * 80 + t] = x[(long)n * 80 + t] + val;
    }
}

extern "C" void kernel_launch(void* const* d_in, const int* in_sizes, int n_in,
                              void* d_out, int out_size, void* d_ws, size_t ws_size,
                              hipStream_t stream) {
    const float* x         = (const float*)d_in[0];
    const float* edge_attr = (const float*)d_in[1];
    const float* Yij       = (const float*)d_in[2];
    const int*   edge_index= (const int*)d_in[3];
    const float* w_emb     = (const float*)d_in[4];
    float* out = (float*)d_out;

    char* ws = (char*)d_ws;
    size_t off = 0;
    unsigned short* emb = (unsigned short*)(ws + off); off += (size_t)E_EDGES * 128 * 2;
    unsigned short* Bt  = (unsigned short*)(ws + off); off += (size_t)3072 * 128 * 2;
    off = (off + 255) & ~(size_t)255;
    float* rT      = (float*)(ws + off); off += (size_t)128 * E_EDGES * 4;
    float* msg     = (float*)(ws + off); off += (size_t)E_EDGES * 96 * 4;
    int*   perm_src= (int*)(ws + off);   off += (size_t)E_EDGES * 4;
    int*   offs    = (int*)(ws + off);   off += (size_t)(NUM_NODES + 1) * 4;
    size_t zoff = off;
    int*   cnt     = (int*)(ws + off);   off += (size_t)NUM_NODES * 4;
    int*   cursor  = (int*)(ws + off);   off += (size_t)NUM_NODES * 4;

    hipMemsetAsync(ws + zoff, 0, (size_t)NUM_NODES * 2 * 4, stream);
    k_wt     <<<(3072 * 128 + 255) / 256, 256, 0, stream>>>(w_emb, Bt);
    k_count  <<<(E_EDGES + 255) / 256, 256, 0, stream>>>(edge_index, cnt);
    k_scan   <<<1, 256, 0, stream>>>(cnt, offs);
    k_scatter<<<(E_EDGES + 255) / 256, 256, 0, stream>>>(edge_index, offs, cursor, perm_src);
    k_prep   <<<E_EDGES / 64, 320, 0, stream>>>(x, edge_attr, Yij, edge_index, emb, rT);
    k_gemm   <<<(E_EDGES + 127) / 128, 256, 0, stream>>>(emb, Bt, rT, Yij, msg);
    k_nodesum<<<NUM_NODES, 128, 0, stream>>>(msg, perm_src, offs, x, out);
}

// Round 8
// 303.746 us; speedup vs baseline: 1.7774x; 1.0544x over previous
//
#include <hip/hip_runtime.h>
#include <hip/hip_bf16.h>

#define E_EDGES 120000
#define NUM_NODES 12000

typedef __attribute__((ext_vector_type(8))) short bfrag;          // 8 bf16
typedef __attribute__((ext_vector_type(8))) unsigned short ushort8;
typedef __attribute__((ext_vector_type(4))) float f32x4;

#define INV_SQRT3 0.57735026918962576f
#define SQRT2_C   1.41421356237309515f
#define N_0E_C    0.14433756729740643f   /* 1/sqrt(48) */
#define NV_C      0.14433756729740643f   /* sqrt(3/48)*1/sqrt(3) = 1/sqrt(48) */
#define WSCALE    0.08838834764831845f   /* 1/sqrt(128) */

__device__ __forceinline__ unsigned short f2bf(float f) {
    union { float f; unsigned int u; } v; v.f = f;
    unsigned int r = v.u + 0x7fffu + ((v.u >> 16) & 1u);
    return (unsigned short)(r >> 16);
}

__device__ __forceinline__ ushort8 pack8(f32x4 a, f32x4 b) {
    ushort8 o;
    o[0] = f2bf(a.x); o[1] = f2bf(a.y); o[2] = f2bf(a.z); o[3] = f2bf(a.w);
    o[4] = f2bf(b.x); o[5] = f2bf(b.y); o[6] = f2bf(b.z); o[7] = f2bf(b.w);
    return o;
}

// ---- Kernel: w_emb (128 x 3072) -> Bt in fragment-consumption order.
__global__ void k_wt(const float* __restrict__ w_emb, unsigned short* __restrict__ Bt) {
    int o = blockIdx.x * 256 + threadIdx.x;
    if (o >= 3072 * 128) return;
    int t = o >> 11;
    int c = (o >> 3) & 255;
    int j = o & 7;
    int kb = c >> 6;
    int quad = (c >> 4) & 3;
    int col = c & 15;
    int k = kb * 32 + quad * 8 + j;
    int n = t * 16 + col;
    Bt[o] = f2bf(w_emb[k * 3072 + n] * WSCALE);
}

// ---- Counting sort by dst: count -> scan -> scatter ----
__global__ void k_count(const int* __restrict__ edge_index, int* __restrict__ cnt) {
    int e = blockIdx.x * 256 + threadIdx.x;
    if (e >= E_EDGES) return;
    atomicAdd(cnt + edge_index[e], 1);
}

__global__ void k_scan(const int* __restrict__ cnt, int* __restrict__ offs) {
    __shared__ int psum[256];
    int t = threadIdx.x;
    const int SEG = (NUM_NODES + 255) / 256;  // 47
    int lo = t * SEG;
    int hi = lo + SEG; if (hi > NUM_NODES) hi = NUM_NODES;
    int s = 0;
    for (int i = lo; i < hi; ++i) s += cnt[i];
    psum[t] = s;
    __syncthreads();
    if (t == 0) {
        int acc = 0;
        for (int i = 0; i < 256; ++i) { int v = psum[i]; psum[i] = acc; acc += v; }
    }
    __syncthreads();
    int acc = psum[t];
    for (int i = lo; i < hi; ++i) { offs[i] = acc; acc += cnt[i]; }
    if (t == 255) offs[NUM_NODES] = acc;   // == E_EDGES
}

__global__ void k_scatter(const int* __restrict__ edge_index, const int* __restrict__ offs,
                          int* __restrict__ cursor, int* __restrict__ perm_src) {
    int e = blockIdx.x * 256 + threadIdx.x;
    if (e >= E_EDGES) return;
    int d = edge_index[e];
    int p = offs[d] + atomicAdd(cursor + d, 1);
    perm_src[p] = e;
}

// ---- Kernel: per-edge prep, wave-sliced, SORTED position space, TILE-MAJOR rT.
// rT layout: [tile p/64][row 0..127][edge-in-tile 0..63] -> each block (= one
// tile of 64 sorted edges) writes ONE CONTIGUOUS 32KB region (stores walk
// +256B), instead of 128 write streams 480KB apart.
// Row content (y0 pre-multiplied as in R0):
//   rows 0..31 xs*y0 | 32..47 vdot*inv3 | 48..79 xs | 80..127 xv*y0
// Wave slices: w0 rows0-31+ys | w1 rows32-63 | w2 rows64-95 | w3 rows96-127
//              | w4 emb pack
__global__ __launch_bounds__(320) void k_prep(
    const float* __restrict__ x, const float* __restrict__ edge_attr,
    const float* __restrict__ Yij, const int* __restrict__ edge_index,
    const int* __restrict__ perm_src,
    unsigned short* __restrict__ emb, float* __restrict__ rT,
    f32x4* __restrict__ ys) {
    const int wid = threadIdx.x >> 6;
    const int lane = threadIdx.x & 63;
    const long p = (long)blockIdx.x * 64 + lane;   // 1875*64 == 120000 exact
    const int eid = perm_src[p];
    const int src = edge_index[E_EDGES + eid];
    const float* xs = x + (long)src * 80;
    const f32x4 y = *(const f32x4*)(Yij + 4 * (long)eid);
    float* tb = rT + (size_t)blockIdx.x * 8192 + lane;   // tile base, this lane

    if (wid == 4) {
        const int dst = edge_index[eid];
        const float* xd = x + (long)dst * 80;
        const float* ea = edge_attr + (long)eid * 64;
        ushort8* embp = (ushort8*)(emb + (long)p * 128);
#pragma unroll
        for (int cb = 0; cb < 4; ++cb)
            embp[cb] = pack8(*(const f32x4*)(xd + cb * 8), *(const f32x4*)(xd + cb * 8 + 4));
#pragma unroll
        for (int cb = 0; cb < 4; ++cb)
            embp[4 + cb] = pack8(*(const f32x4*)(xs + cb * 8), *(const f32x4*)(xs + cb * 8 + 4));
#pragma unroll
        for (int cb = 0; cb < 8; ++cb)
            embp[8 + cb] = pack8(*(const f32x4*)(ea + cb * 8), *(const f32x4*)(ea + cb * 8 + 4));
    } else if (wid == 0) {
        const float y0 = y.x;
#pragma unroll
        for (int i = 0; i < 8; ++i) {
            f32x4 v = *(const f32x4*)(xs + i * 4);
            tb[(4 * i + 0) * 64] = v.x * y0;
            tb[(4 * i + 1) * 64] = v.y * y0;
            tb[(4 * i + 2) * 64] = v.z * y0;
            tb[(4 * i + 3) * 64] = v.w * y0;
        }
        ys[p] = y;
    } else if (wid == 1) {
        const float y1a = y.y, y1b = y.z, y1c = y.w;
        float xv[48];
#pragma unroll
        for (int i = 0; i < 12; ++i) {
            f32x4 v = *(const f32x4*)(xs + 32 + i * 4);
            xv[4 * i] = v.x; xv[4 * i + 1] = v.y; xv[4 * i + 2] = v.z; xv[4 * i + 3] = v.w;
        }
#pragma unroll
        for (int u = 0; u < 16; ++u)
            tb[(32 + u) * 64] =
                (xv[3 * u] * y1a + xv[3 * u + 1] * y1b + xv[3 * u + 2] * y1c) * INV_SQRT3;
#pragma unroll
        for (int i = 0; i < 4; ++i) {
            f32x4 v = *(const f32x4*)(xs + i * 4);
            tb[(48 + 4 * i + 0) * 64] = v.x;
            tb[(48 + 4 * i + 1) * 64] = v.y;
            tb[(48 + 4 * i + 2) * 64] = v.z;
            tb[(48 + 4 * i + 3) * 64] = v.w;
        }
    } else if (wid == 2) {
        const float y0 = y.x;
#pragma unroll
        for (int i = 0; i < 4; ++i) {
            f32x4 v = *(const f32x4*)(xs + 16 + i * 4);
            tb[(64 + 4 * i + 0) * 64] = v.x;
            tb[(64 + 4 * i + 1) * 64] = v.y;
            tb[(64 + 4 * i + 2) * 64] = v.z;
            tb[(64 + 4 * i + 3) * 64] = v.w;
        }
#pragma unroll
        for (int i = 0; i < 4; ++i) {
            f32x4 v = *(const f32x4*)(xs + 32 + i * 4);
            tb[(80 + 4 * i + 0) * 64] = v.x * y0;
            tb[(80 + 4 * i + 1) * 64] = v.y * y0;
            tb[(80 + 4 * i + 2) * 64] = v.z * y0;
            tb[(80 + 4 * i + 3) * 64] = v.w * y0;
        }
    } else {  // wid == 3
        const float y0 = y.x;
#pragma unroll
        for (int i = 0; i < 8; ++i) {
            f32x4 v = *(const f32x4*)(xs + 48 + i * 4);
            tb[(96 + 4 * i + 0) * 64] = v.x * y0;
            tb[(96 + 4 * i + 1) * 64] = v.y * y0;
            tb[(96 + 4 * i + 2) * 64] = v.z * y0;
            tb[(96 + 4 * i + 3) * 64] = v.w * y0;
        }
    }
}

// ---- Kernel: fused GEMM + u-contraction — R6/R7 loop, instruction-identical.
// Only addressing changes: loadw reads tile-major rT (rbase + r*64, walks a
// 32KB-local region); epilogue reads ys[e] (16B vector) and stores msg[e][96]
// in sorted position space (no atomics).
__global__ __launch_bounds__(256, 4) void k_gemm(
    const unsigned short* __restrict__ emb, const unsigned short* __restrict__ Bt,
    const float* __restrict__ rT, const f32x4* __restrict__ ys,
    float* __restrict__ msg) {
    const int lane = threadIdx.x & 63;
    const int wave = threadIdx.x >> 6;
    long e0 = (long)blockIdx.x * 128 + (long)wave * 32;
    const bool dup = (e0 + 32 > E_EDGES);
    if (dup) e0 = E_EDGES - 32;
    const int col = lane & 15, quad = lane >> 4;

    __shared__ __align__(16) char lds[2][16384];

    // A fragments, register-resident for the whole sweep
    bfrag A[2][4];
#pragma unroll
    for (int s = 0; s < 2; ++s) {
        const unsigned short* ap = emb + (e0 + s * 16 + col) * 128 + quad * 8;
#pragma unroll
        for (int kb = 0; kb < 4; ++kb) A[s][kb] = *(const bfrag*)(ap + kb * 32);
    }

    auto stage = [&](int ci) {
        const char* g = (const char*)Bt + (size_t)ci * 16384 + wave * 4096 + lane * 16;
        char* l = &lds[ci & 1][wave * 4096];
#pragma unroll
        for (int j = 0; j < 4; ++j)
            __builtin_amdgcn_global_load_lds(
                (const __attribute__((address_space(1))) unsigned int*)(g + j * 1024),
                (__attribute__((address_space(3))) unsigned int*)(l + j * 1024), 16, 0, 0);
    };

    f32x4 z = {0.f, 0.f, 0.f, 0.f};
    f32x4 acc_s0[2] = {z, z}, acc_s1[2] = {z, z}, acc_g[2] = {z, z}, acc_t5[2] = {z, z};
    f32x4 acc_v[2][3] = {{z, z, z}, {z, z, z}};

    // Tile-major rT: tile = e0>>6 (one 128x64 fp32 tile = 32KB), half = e0&32.
    const float* rbase = rT + ((size_t)(e0 >> 6)) * 8192 + (e0 & 32) + quad * 4;
    auto loadw = [&](int r, f32x4& a, f32x4& b) {
        const float* p = rbase + r * 64;
        a = *(const f32x4*)(p);
        b = *(const f32x4*)(p + 16);
    };

    auto tile = [&](const char* lt, f32x4& c0, f32x4& c1) {
        bfrag B0 = *(const bfrag*)(lt + lane * 16);
        bfrag B1 = *(const bfrag*)(lt + lane * 16 + 1024);
        bfrag B2 = *(const bfrag*)(lt + lane * 16 + 2048);
        bfrag B3 = *(const bfrag*)(lt + lane * 16 + 3072);
        c0 = z; c1 = z;
        c0 = __builtin_amdgcn_mfma_f32_16x16x32_bf16(A[0][0], B0, c0, 0, 0, 0);
        c1 = __builtin_amdgcn_mfma_f32_16x16x32_bf16(A[1][0], B0, c1, 0, 0, 0);
        c0 = __builtin_amdgcn_mfma_f32_16x16x32_bf16(A[0][1], B1, c0, 0, 0, 0);
        c1 = __builtin_amdgcn_mfma_f32_16x16x32_bf16(A[1][1], B1, c1, 0, 0, 0);
        c0 = __builtin_amdgcn_mfma_f32_16x16x32_bf16(A[0][2], B2, c0, 0, 0, 0);
        c1 = __builtin_amdgcn_mfma_f32_16x16x32_bf16(A[1][2], B2, c1, 0, 0, 0);
        c0 = __builtin_amdgcn_mfma_f32_16x16x32_bf16(A[0][3], B3, c0, 0, 0, 0);
        c1 = __builtin_amdgcn_mfma_f32_16x16x32_bf16(A[1][3], B3, c1, 0, 0, 0);
    };

    stage(0);
    int cidx = 0;
    auto nextbuf = [&]() -> const char* {
        __syncthreads();
        if (cidx + 1 < 48) stage(cidx + 1);
        const char* b = lds[cidx & 1];
        ++cidx;
        return b;
    };

    f32x4 c0, c1;

    // W1: chunks 0..15, rows 2j,2j+1 -> acc_s
    {
        f32x4 p0a, p0b, p1a, p1b;
        loadw(0, p0a, p0b); loadw(1, p1a, p1b);
#pragma unroll 1
        for (int j = 0; j < 16; ++j) {
            const char* buf = nextbuf();
            f32x4 w0a = p0a, w0b = p0b, w1a = p1a, w1b = p1b;
            int nr = (j < 15) ? (2 * j + 2) : 0;
            loadw(nr, p0a, p0b); loadw(nr + 1, p1a, p1b);
            tile(buf,         c0, c1); acc_s0[0] += c0 * w0a; acc_s0[1] += c1 * w0b;
            tile(buf + 4096,  c0, c1); acc_s1[0] += c0 * w0a; acc_s1[1] += c1 * w0b;
            tile(buf + 8192,  c0, c1); acc_s0[0] += c0 * w1a; acc_s0[1] += c1 * w1b;
            tile(buf + 12288, c0, c1); acc_s1[0] += c0 * w1a; acc_s1[1] += c1 * w1b;
        }
    }
    // W2: chunks 16..23, rows 4j..4j+3 -> acc_g
    {
        f32x4 pa[4], pb[4];
#pragma unroll
        for (int i = 0; i < 4; ++i) loadw(i, pa[i], pb[i]);
#pragma unroll 1
        for (int j = 0; j < 8; ++j) {
            const char* buf = nextbuf();
            f32x4 wa[4], wb[4];
#pragma unroll
            for (int i = 0; i < 4; ++i) { wa[i] = pa[i]; wb[i] = pb[i]; }
            int nr = (j < 7) ? (4 * j + 4) : 0;
#pragma unroll
            for (int i = 0; i < 4; ++i) loadw(nr + i, pa[i], pb[i]);
#pragma unroll
            for (int i = 0; i < 4; ++i) {
                tile(buf + i * 4096, c0, c1);
                acc_g[0] += c0 * wa[i]; acc_g[1] += c1 * wb[i];
            }
        }
    }
    // W3: chunks 24..31, rows 32+2j,33+2j -> acc_s
    {
        f32x4 p0a, p0b, p1a, p1b;
        loadw(32, p0a, p0b); loadw(33, p1a, p1b);
#pragma unroll 1
        for (int j = 0; j < 8; ++j) {
            const char* buf = nextbuf();
            f32x4 w0a = p0a, w0b = p0b, w1a = p1a, w1b = p1b;
            int nr = (j < 7) ? (32 + 2 * j + 2) : 32;
            loadw(nr, p0a, p0b); loadw(nr + 1, p1a, p1b);
            tile(buf,         c0, c1); acc_s0[0] += c0 * w0a; acc_s0[1] += c1 * w0b;
            tile(buf + 4096,  c0, c1); acc_s1[0] += c0 * w0a; acc_s1[1] += c1 * w0b;
            tile(buf + 8192,  c0, c1); acc_s0[0] += c0 * w1a; acc_s0[1] += c1 * w1b;
            tile(buf + 12288, c0, c1); acc_s1[0] += c0 * w1a; acc_s1[1] += c1 * w1b;
        }
    }
    // W4: chunks 32..35, rows 32+4j+i -> acc_g
    {
        f32x4 pa[4], pb[4];
#pragma unroll
        for (int i = 0; i < 4; ++i) loadw(32 + i, pa[i], pb[i]);
#pragma unroll 1
        for (int j = 0; j < 4; ++j) {
            const char* buf = nextbuf();
            f32x4 wa[4], wb[4];
#pragma unroll
            for (int i = 0; i < 4; ++i) { wa[i] = pa[i]; wb[i] = pb[i]; }
            int nr = (j < 3) ? (32 + 4 * j + 4) : 32;
#pragma unroll
            for (int i = 0; i < 4; ++i) loadw(nr + i, pa[i], pb[i]);
#pragma unroll
            for (int i = 0; i < 4; ++i) {
                tile(buf + i * 4096, c0, c1);
                acc_g[0] += c0 * wa[i]; acc_g[1] += c1 * wb[i];
            }
        }
    }
    // W5: chunks 36..43, rows 48+4j+i -> acc_t5
    {
        f32x4 pa[4], pb[4];
#pragma unroll
        for (int i = 0; i < 4; ++i) loadw(48 + i, pa[i], pb[i]);
#pragma unroll 1
        for (int j = 0; j < 8; ++j) {
            const char* buf = nextbuf();
            f32x4 wa[4], wb[4];
#pragma unroll
            for (int i = 0; i < 4; ++i) { wa[i] = pa[i]; wb[i] = pb[i]; }
            int nr = (j < 7) ? (48 + 4 * j + 4) : 48;
#pragma unroll
            for (int i = 0; i < 4; ++i) loadw(nr + i, pa[i], pb[i]);
#pragma unroll
            for (int i = 0; i < 4; ++i) {
                tile(buf + i * 4096, c0, c1);
                acc_t5[0] += c0 * wa[i]; acc_t5[1] += c1 * wb[i];
            }
        }
    }
    // W6: chunks 44..47, u=4j+i, rows 80+3u+k -> acc_v[k]
    {
        f32x4 va[3], vb[3];
#pragma unroll
        for (int k = 0; k < 3; ++k) loadw(80 + k, va[k], vb[k]);
#pragma unroll 1
        for (int j = 0; j < 4; ++j) {
            const char* buf = nextbuf();
#pragma unroll
            for (int i = 0; i < 4; ++i) {
                f32x4 wa[3], wb[3];
#pragma unroll
                for (int k = 0; k < 3; ++k) { wa[k] = va[k]; wb[k] = vb[k]; }
                int un = 4 * j + i + 1; if (un > 15) un = 0;
#pragma unroll
                for (int k = 0; k < 3; ++k) loadw(80 + 3 * un + k, va[k], vb[k]);
                tile(buf + i * 4096, c0, c1);
#pragma unroll
                for (int k = 0; k < 3; ++k) {
                    acc_v[0][k] += c0 * wa[k];
                    acc_v[1][k] += c1 * wb[k];
                }
            }
        }
    }

    if (dup) return;
    // Epilogue: scale + coalesced stores into msg[e][96] (sorted space).
#pragma unroll
    for (int s = 0; s < 2; ++s) {
        long eb = e0 + s * 16 + quad * 4;
#pragma unroll
        for (int r = 0; r < 4; ++r) {
            long e = eb + r;
            float* base = msg + e * 96;
            f32x4 y = ys[e];
            float y1a = y.y, y1b = y.z, y1c = y.w;
            base[col]            = N_0E_C * acc_s0[s][r];
            base[col + 16]       = N_0E_C * acc_s1[s][r];
            base[32 + col]       = N_0E_C * acc_g[s][r];
            float t5 = acc_t5[s][r];
            base[48 + col * 3 + 0] = NV_C * (t5 * y1a + acc_v[s][0][r]);
            base[48 + col * 3 + 1] = NV_C * (t5 * y1b + acc_v[s][1][r]);
            base[48 + col * 3 + 2] = NV_C * (t5 * y1c + acc_v[s][2][r]);
        }
    }
}

// ---- Kernel: per-node sum over CONTIGUOUS sorted msg rows + mean, relu-gate,
// residual. One block per node, 128 threads; reads stream linearly.
__global__ __launch_bounds__(128) void k_nodesum(
    const float* __restrict__ msg, const int* __restrict__ offs,
    const float* __restrict__ x, float* __restrict__ out) {
    int n = blockIdx.x;
    int t = threadIdx.x;
    int lo = offs[n], hi = offs[n + 1];
    float s = 0.0f;
    if (t < 96) {
        const float* mp = msg + (size_t)lo * 96 + t;
        for (int i = lo; i < hi; ++i, mp += 96) s += *mp;
    }
    float inv = 1.0f / fmaxf((float)(hi - lo), 1.0f);
    __shared__ float sm[96];
    if (t < 96) sm[t] = s * inv;
    __syncthreads();
    if (t < 80) {
        float val;
        if (t < 32) {
            val = SQRT2_C * fmaxf(sm[t], 0.0f);
        } else {
            int j = t - 32;
            int w = j / 3;
            float g = SQRT2_C * fmaxf(sm[32 + w], 0.0f);
            val = sm[48 + j] * g;
        }
        out[(long)n * 80 + t] = x[(long)n * 80 + t] + val;
    }
}

extern "C" void kernel_launch(void* const* d_in, const int* in_sizes, int n_in,
                              void* d_out, int out_size, void* d_ws, size_t ws_size,
                              hipStream_t stream) {
    const float* x         = (const float*)d_in[0];
    const float* edge_attr = (const float*)d_in[1];
    const float* Yij       = (const float*)d_in[2];
    const int*   edge_index= (const int*)d_in[3];
    const float* w_emb     = (const float*)d_in[4];
    float* out = (float*)d_out;

    char* ws = (char*)d_ws;
    size_t off = 0;
    unsigned short* emb = (unsigned short*)(ws + off); off += (size_t)E_EDGES * 128 * 2;
    unsigned short* Bt  = (unsigned short*)(ws + off); off += (size_t)3072 * 128 * 2;
    off = (off + 255) & ~(size_t)255;
    float* rT      = (float*)(ws + off); off += (size_t)128 * E_EDGES * 4;
    float* msg     = (float*)(ws + off); off += (size_t)E_EDGES * 96 * 4;
    f32x4* ys      = (f32x4*)(ws + off); off += (size_t)E_EDGES * 16;
    int*   perm_src= (int*)(ws + off);   off += (size_t)E_EDGES * 4;
    int*   offs    = (int*)(ws + off);   off += (size_t)(NUM_NODES + 1) * 4;
    size_t zoff = off;
    int*   cnt     = (int*)(ws + off);   off += (size_t)NUM_NODES * 4;
    int*   cursor  = (int*)(ws + off);   off += (size_t)NUM_NODES * 4;

    hipMemsetAsync(ws + zoff, 0, (size_t)NUM_NODES * 2 * 4, stream);
    k_wt     <<<(3072 * 128 + 255) / 256, 256, 0, stream>>>(w_emb, Bt);
    k_count  <<<(E_EDGES + 255) / 256, 256, 0, stream>>>(edge_index, cnt);
    k_scan   <<<1, 256, 0, stream>>>(cnt, offs);
    k_scatter<<<(E_EDGES + 255) / 256, 256, 0, stream>>>(edge_index, offs, cursor, perm_src);
    k_prep   <<<E_EDGES / 64, 320, 0, stream>>>(x, edge_attr, Yij, edge_index, perm_src,
                                                emb, rT, ys);
    k_gemm   <<<(E_EDGES + 127) / 128, 256, 0, stream>>>(emb, Bt, rT, ys, msg);
    k_nodesum<<<NUM_NODES, 128, 0, stream>>>(msg, offs, x, out);
}